// Round 4
// baseline (3690.743 us; speedup 1.0000x reference)
//
#include <hip/hip_runtime.h>
#include <math.h>

#define BATCH 4
#define P 3072
#define NROW (BATCH * P)        // 12288
#define NTILE (NROW / 16)       // 768 row-tiles of 16 rows
#define TPB (P / 16)            // 192 tiles per batch
#define MAXIT 50
#define NBLK 256                // persistent blocks, 1 per CU (cap is 4/CU -> co-resident)
#define RPB 48                  // rows per block (3 row-tiles)
#define CTW 24                  // col-tiles per wave (8 waves x 24 x 16 = 3072 cols)

#define LN2 0.69314718055994531f
#define INV_LN2 1.44269504088896341f

typedef _Float16 f16x8 __attribute__((ext_vector_type(8)));
typedef float f32x4 __attribute__((ext_vector_type(4)));

__device__ inline float waveReduceSum(float v) {
#pragma unroll
  for (int off = 32; off > 0; off >>= 1) v += __shfl_xor(v, off, 64);
  return v;
}
__device__ inline float fexp2(float x) { return __builtin_amdgcn_exp2f(x); }
__device__ inline float flog2(float x) { return __builtin_amdgcn_logf(x); }  // v_log_f32 = log2

// Device-scope grid barrier (256 co-resident blocks). __threadfence() on both
// sides gives release/acquire at agent scope -> cross-XCD L2 coherence for the
// bias vectors that cross iterations (G16 hazard).
__device__ inline void gridBarrier(int* cnt, int* gen) {
  __syncthreads();
  if (threadIdx.x == 0) {
    int g = __hip_atomic_load(gen, __ATOMIC_RELAXED, __HIP_MEMORY_SCOPE_AGENT);
    __threadfence();                       // release all prior writes
    int a = __hip_atomic_fetch_add(cnt, 1, __ATOMIC_RELAXED, __HIP_MEMORY_SCOPE_AGENT);
    if (a == NBLK - 1) {
      __hip_atomic_store(cnt, 0, __ATOMIC_RELAXED, __HIP_MEMORY_SCOPE_AGENT);
      __hip_atomic_store(gen, g + 1, __ATOMIC_RELAXED, __HIP_MEMORY_SCOPE_AGENT);
    } else {
      while (__hip_atomic_load(gen, __ATOMIC_RELAXED, __HIP_MEMORY_SCOPE_AGENT) == g)
        __builtin_amdgcn_s_sleep(4);
    }
    __threadfence();                       // acquire: drop stale cached lines
  }
  __syncthreads();
}

// Pack x/y into MFMA-fragment-major fp16 tiles: frag[tile][g][r][8] (1 KB/tile),
// so lane l loads its fragment for tile T at byte T*1024 + l*16 (coalesced 1 KB
// wave-load). x pre-scaled by 20/ln2 -> MFMA yields the base-2 LSE cross term.
__global__ __launch_bounds__(256) void prep_kernel(const float* __restrict__ x,
                                                   const float* __restrict__ y,
                                                   _Float16* __restrict__ xh,
                                                   _Float16* __restrict__ yh,
                                                   float* __restrict__ x2,
                                                   float* __restrict__ y2,
                                                   float* __restrict__ vb) {
  int t = threadIdx.x;
  int lane = t & 63;
  int g = lane >> 4, r = lane & 15;
  int tileG = blockIdx.x * 4 + (t >> 6);     // 0..1535 (x tiles then y tiles)
  int isY = tileG >= NTILE;
  int tile = isY ? (tileG - NTILE) : tileG;
  const float* src = isY ? y : x;
  int row = tile * 16 + r;
  const float* p = src + (size_t)row * 32 + g * 8;
  float4 v0 = *(const float4*)p;
  float4 v1 = *(const float4*)(p + 4);
  float sq = v0.x * v0.x + v0.y * v0.y + v0.z * v0.z + v0.w * v0.w +
             v1.x * v1.x + v1.y * v1.y + v1.z * v1.z + v1.w * v1.w;
  sq += __shfl_xor(sq, 16, 64);
  sq += __shfl_xor(sq, 32, 64);              // lanes with same r hold the row sum
  float scale = isY ? 1.0f : 20.0f * INV_LN2;
  f16x8 h;
  h[0] = (_Float16)(scale * v0.x); h[1] = (_Float16)(scale * v0.y);
  h[2] = (_Float16)(scale * v0.z); h[3] = (_Float16)(scale * v0.w);
  h[4] = (_Float16)(scale * v1.x); h[5] = (_Float16)(scale * v1.y);
  h[6] = (_Float16)(scale * v1.z); h[7] = (_Float16)(scale * v1.w);
  _Float16* dst = (isY ? yh : xh) + (size_t)tile * 512 + lane * 8;
  *(f16x8*)dst = h;
  if (lane < 16) {
    if (isY) { y2[row] = sq; vb[row] = -10.0f * INV_LN2 * sq; }  // v=0 bias
    else     { x2[row] = sq; }
  }
}

// Persistent Sinkhorn loop. 256 blocks x 512 threads; block owns 48 rows of x
// AND the same 48 rows of y; 8 waves partition the 3072 cols (24 col-tiles each).
// Per iteration: u-phase (A=x rows, B=yh, bias=vb), barrier, [block0: err->done],
// v-phase (A=y rows, B=xh, bias=ub), barrier, early-exit check.
__global__ __launch_bounds__(512, 2) void sinkhorn_kernel(
    const _Float16* __restrict__ xh, const _Float16* __restrict__ yh,
    float* __restrict__ u, float* __restrict__ v,
    float* __restrict__ ub, float* __restrict__ vb,
    const float* __restrict__ x2, const float* __restrict__ y2,
    float* __restrict__ errpart, int* __restrict__ bar, float lmn) {
  int tid = threadIdx.x;
  int lane = tid & 63;
  int w = tid >> 6;
  int rsel = lane & 15;
  int bid = blockIdx.x;
  int b = bid >> 6;                          // 64 blocks per batch
  int tile0 = bid * 3;
  int gr0 = bid * RPB;
  // A-fragments for both phases: loaded ONCE, live in registers for 50 iters.
  f16x8 xfr[3], yfr[3];
#pragma unroll
  for (int rt = 0; rt < 3; ++rt) {
    xfr[rt] = *(const f16x8*)(xh + (size_t)(tile0 + rt) * 512 + lane * 8);
    yfr[rt] = *(const f16x8*)(yh + (size_t)(tile0 + rt) * 512 + lane * 8);
  }
  size_t jbase = ((size_t)(b * TPB + w * CTW)) * 512 + lane * 8;
  const _Float16* BxP = xh + jbase;
  const _Float16* ByP = yh + jbase;
  int biasoff = b * P + w * (CTW * 16) + rsel;

  __shared__ float lm[8][RPB], ls[8][RPB];
  __shared__ int sdone;

  auto halfstep = [&](const f16x8* afr, const _Float16* Bp, const float* biasIn,
                      const float* nrm, float* pot, float* biasOut, bool trackErr) {
    const float* biasp = biasIn + biasoff;
    float m[3][4], s[3][4];
#pragma unroll
    for (int rt = 0; rt < 3; ++rt)
#pragma unroll
      for (int r = 0; r < 4; ++r) { m[rt][r] = -1e30f; s[rt][r] = 0.f; }
#pragma unroll 2
    for (int c = 0; c < 6; ++c) {            // 6 chunks x 4 col-tiles
      f16x8 bfr[4];
      float bb[4];
#pragma unroll
      for (int t4 = 0; t4 < 4; ++t4) {
        bfr[t4] = *(const f16x8*)(Bp + ((size_t)(c * 4 + t4) << 9));  // coalesced 1 KB
        bb[t4] = biasp[(c * 4 + t4) * 16];
      }
      f32x4 acc[3][4];
#pragma unroll
      for (int rt = 0; rt < 3; ++rt)
#pragma unroll
        for (int t4 = 0; t4 < 4; ++t4) {
          f32x4 ci = {bb[t4], bb[t4], bb[t4], bb[t4]};
          acc[rt][t4] = __builtin_amdgcn_mfma_f32_16x16x32_f16(afr[rt], bfr[t4], ci, 0, 0, 0);
        }
      // online LSE (base 2); rescale only when some lane's chunk-max beats m
#pragma unroll
      for (int rt = 0; rt < 3; ++rt)
#pragma unroll
        for (int r = 0; r < 4; ++r) {
          float a0 = acc[rt][0][r], a1 = acc[rt][1][r], a2 = acc[rt][2][r], a3 = acc[rt][3][r];
          float cm = fmaxf(fmaxf(a0, a1), fmaxf(a2, a3));
          if (__any(cm > m[rt][r])) {
            float nm = fmaxf(m[rt][r], cm);
            s[rt][r] = s[rt][r] * fexp2(m[rt][r] - nm) +
                       fexp2(a0 - nm) + fexp2(a1 - nm) + fexp2(a2 - nm) + fexp2(a3 - nm);
            m[rt][r] = nm;
          } else {
            float mm = m[rt][r];
            s[rt][r] += fexp2(a0 - mm) + fexp2(a1 - mm) + fexp2(a2 - mm) + fexp2(a3 - mm);
          }
        }
    }
    // butterfly merge across the 16-lane col groups (rows fixed: xor bits 0-3)
#pragma unroll
    for (int rt = 0; rt < 3; ++rt)
#pragma unroll
      for (int r = 0; r < 4; ++r) {
#pragma unroll
        for (int off = 1; off < 16; off <<= 1) {
          float om = __shfl_xor(m[rt][r], off, 64);
          float os = __shfl_xor(s[rt][r], off, 64);
          float nm = fmaxf(m[rt][r], om);
          s[rt][r] = s[rt][r] * fexp2(m[rt][r] - nm) + os * fexp2(om - nm);
          m[rt][r] = nm;
        }
      }
    __syncthreads();                          // lm/ls reuse guard
    if (rsel == 0) {
      int g = lane >> 4;
#pragma unroll
      for (int rt = 0; rt < 3; ++rt)
#pragma unroll
        for (int r = 0; r < 4; ++r) {
          lm[w][rt * 16 + g * 4 + r] = m[rt][r];
          ls[w][rt * 16 + g * 4 + r] = s[rt][r];
        }
    }
    __syncthreads();
    float e = 0.f;
    if (tid < RPB) {
      float M = lm[0][tid], S = ls[0][tid];
#pragma unroll
      for (int w2 = 1; w2 < 8; ++w2) {
        float om = lm[w2][tid], os = ls[w2][tid];
        float nm = fmaxf(M, om);
        S = S * fexp2(M - nm) + os * fexp2(om - nm);
        M = nm;
      }
      float L2v = M + flog2(S);
      int gi = gr0 + tid;
      float nv = 0.1f * lmn + nrm[gi] - 0.1f * LN2 * L2v;
      if (trackErr) e = fabsf(nv - pot[gi]);
      pot[gi] = nv;
      biasOut[gi] = 10.0f * INV_LN2 * (nv - nrm[gi]);
    }
    if (trackErr && tid < 64) {
      e = waveReduceSum(e);
      if (tid == 0) errpart[bid] = e;
    }
  };

  for (int it = 0; it < MAXIT; ++it) {
    halfstep(xfr, ByP, vb, x2, u, ub, true);        // u update
    gridBarrier(bar, bar + 1);
    if (bid == 0 && tid < 64) {                     // errpart complete after barrier
      float ts = errpart[tid] + errpart[tid + 64] +
                 errpart[tid + 128] + errpart[tid + 192];
      ts = waveReduceSum(ts);
      if (tid == 0)
        __hip_atomic_store(bar + 2, (ts * 0.25f < 0.1f) ? 1 : 0,
                           __ATOMIC_RELAXED, __HIP_MEMORY_SCOPE_AGENT);
    }
    halfstep(yfr, BxP, ub, y2, v, vb, false);       // v update
    gridBarrier(bar, bar + 1);
    if (tid == 0)
      sdone = __hip_atomic_load(bar + 2, __ATOMIC_RELAXED, __HIP_MEMORY_SCOPE_AGENT);
    __syncthreads();
    if (sdone) break;                                // freeze u,v (matches reference)
  }
}

// Single fused epilogue: exact fp32 C, pi = exp((u+v-C)*10), cost partials.
__global__ __launch_bounds__(256) void final_kernel(const float* __restrict__ x,
                                                    const float* __restrict__ y,
                                                    const float* __restrict__ x2,
                                                    const float* __restrict__ y2,
                                                    const float* __restrict__ u,
                                                    const float* __restrict__ v,
                                                    float* __restrict__ C,
                                                    float* __restrict__ pi,
                                                    float* __restrict__ costpart) {
  __shared__ float xs[64][33];
  __shared__ float ys[64][33];
  int t = threadIdx.x;
  int b = blockIdx.z;
  int i0 = blockIdx.x * 64;
  int j0 = blockIdx.y * 64;
  const float4* xg = (const float4*)(x + ((size_t)b * P + i0) * 32);
  const float4* yg = (const float4*)(y + ((size_t)b * P + j0) * 32);
#pragma unroll
  for (int k = 0; k < 2; ++k) {
    int f4 = t + k * 256;
    int row = f4 >> 3;
    int col = (f4 & 7) << 2;
    float4 xv = xg[f4];
    xs[row][col] = xv.x; xs[row][col + 1] = xv.y; xs[row][col + 2] = xv.z; xs[row][col + 3] = xv.w;
    float4 yv = yg[f4];
    ys[row][col] = yv.x; ys[row][col + 1] = yv.y; ys[row][col + 2] = yv.z; ys[row][col + 3] = yv.w;
  }
  __syncthreads();
  int ti = t >> 4, tj = t & 15;
  int ib = ti * 4, jb = tj * 4;
  float acc[4][4];
#pragma unroll
  for (int a = 0; a < 4; ++a)
#pragma unroll
    for (int bb = 0; bb < 4; ++bb) acc[a][bb] = 0.f;
#pragma unroll 8
  for (int k = 0; k < 32; ++k) {
    float xa[4], yb[4];
#pragma unroll
    for (int a = 0; a < 4; ++a) xa[a] = xs[ib + a][k];
#pragma unroll
    for (int bb = 0; bb < 4; ++bb) yb[bb] = ys[jb + bb][k];
#pragma unroll
    for (int a = 0; a < 4; ++a)
#pragma unroll
      for (int bb = 0; bb < 4; ++bb) acc[a][bb] = fmaf(xa[a], yb[bb], acc[a][bb]);
  }
  float y2r[4], vr[4];
#pragma unroll
  for (int bb = 0; bb < 4; ++bb) {
    y2r[bb] = y2[b * P + j0 + jb + bb];
    vr[bb] = v[b * P + j0 + jb + bb];
  }
  float costacc = 0.f;
#pragma unroll
  for (int a = 0; a < 4; ++a) {
    int gi = b * P + i0 + ib + a;
    float x2r = x2[gi];
    float ur = u[gi];
    float4 co, po;
    co.x = x2r + y2r[0] - 2.f * acc[a][0];
    co.y = x2r + y2r[1] - 2.f * acc[a][1];
    co.z = x2r + y2r[2] - 2.f * acc[a][2];
    co.w = x2r + y2r[3] - 2.f * acc[a][3];
    po.x = __expf((ur + vr[0] - co.x) * 10.f);
    po.y = __expf((ur + vr[1] - co.y) * 10.f);
    po.z = __expf((ur + vr[2] - co.z) * 10.f);
    po.w = __expf((ur + vr[3] - co.w) * 10.f);
    costacc += po.x * co.x + po.y * co.y + po.z * co.z + po.w * co.w;
    float* crow = C + (size_t)gi * P + j0;
    ((float4*)crow)[tj] = co;
    float* prow = pi + (size_t)gi * P + j0;
    ((float4*)prow)[tj] = po;
  }
  costacc = waveReduceSum(costacc);
  __shared__ float red[4];
  if ((t & 63) == 0) red[t >> 6] = costacc;
  __syncthreads();
  if (t == 0)
    costpart[((size_t)b * 48 + blockIdx.y) * 48 + blockIdx.x] =
        red[0] + red[1] + red[2] + red[3];
}

__global__ __launch_bounds__(256) void cost_kernel(const float* __restrict__ costpart,
                                                   float* __restrict__ cost) {
  __shared__ float red[4];
  int t = threadIdx.x;
  for (int b = 0; b < BATCH; ++b) {
    float loc = 0.f;
    for (int idx = t; idx < 2304; idx += 256) loc += costpart[b * 2304 + idx];
    loc = waveReduceSum(loc);
    if ((t & 63) == 0) red[t >> 6] = loc;
    __syncthreads();
    if (t == 0) cost[b] = red[0] + red[1] + red[2] + red[3];
    __syncthreads();
  }
}

extern "C" void kernel_launch(void* const* d_in, const int* in_sizes, int n_in,
                              void* d_out, int out_size, void* d_ws, size_t ws_size,
                              hipStream_t stream) {
  (void)in_sizes; (void)n_in; (void)out_size; (void)ws_size;
  const float* x = (const float*)d_in[0];
  const float* y = (const float*)d_in[1];
  float* out = (float*)d_out;
  float* cost = out;                          // [4]
  float* pi = out + 4;                        // [4*3072*3072]
  float* C = pi + (size_t)BATCH * P * P;      // [4*3072*3072]

  float* u = (float*)d_ws;                    // 12288
  int* bar = (int*)(u + NROW);                // 64 ints: cnt, gen, done
  float* v = (float*)(bar + 64);              // 12288
  float* ub = v + NROW;                       // 12288  (10/ln2*(u - x2))
  float* vb = ub + NROW;                      // 12288  (10/ln2*(v - y2))
  float* x2 = vb + NROW;                      // 12288
  float* y2 = x2 + NROW;                      // 12288
  float* errpart = y2 + NROW;                 // 256
  float* costpart = errpart + NBLK;           // 9216

  // fp16 fragment-packed scratch lives in the C output region (written last)
  _Float16* xh = (_Float16*)C;                // [768 tiles][1 KB] = 20/ln2 * x
  _Float16* yh = xh + (size_t)NROW * 32;      // [768 tiles][1 KB] = y

  // zero u + barrier state (harness poisons ws each call)
  hipMemsetAsync(d_ws, 0, (size_t)NROW * sizeof(float) + 64 * sizeof(int), stream);

  float lmn = logf(1.0f / 3072.0f + 1e-8f);   // log_mu == log_nu

  prep_kernel<<<384, 256, 0, stream>>>(x, y, xh, yh, x2, y2, vb);
  sinkhorn_kernel<<<NBLK, 512, 0, stream>>>(xh, yh, u, v, ub, vb, x2, y2,
                                            errpart, bar, lmn);
  final_kernel<<<dim3(48, 48, 4), 256, 0, stream>>>(x, y, x2, y2, u, v, C, pi, costpart);
  cost_kernel<<<1, 256, 0, stream>>>(costpart, cost);
}

// Round 5
// 3140.316 us; speedup vs baseline: 1.1753x; 1.1753x over previous
//
#include <hip/hip_runtime.h>
#include <math.h>

#define BATCH 4
#define P 3072
#define NROW (BATCH * P)        // 12288
#define NTILE (NROW / 16)       // 768 row-tiles of 16 rows
#define TPB (P / 16)            // 192 tiles per batch
#define MAXIT 50
#define NBLK 256                // persistent blocks, 1 per CU
#define RPB 48                  // rows per block (3 row-tiles)
#define CTW 24                  // col-tiles per wave (8 waves x 24 x 16 = 3072 cols)

#define LN2 0.69314718055994531f
#define INV_LN2 1.44269504088896341f

typedef _Float16 f16x8 __attribute__((ext_vector_type(8)));
typedef float f32x4 __attribute__((ext_vector_type(4)));

__device__ inline float waveReduceSum(float v) {
#pragma unroll
  for (int off = 32; off > 0; off >>= 1) v += __shfl_xor(v, off, 64);
  return v;
}
__device__ inline float fexp2(float x) { return __builtin_amdgcn_exp2f(x); }
__device__ inline float flog2(float x) { return __builtin_amdgcn_logf(x); }  // v_log_f32 = log2

// Device-scope grid barrier (256 co-resident blocks). __threadfence() on both
// sides -> release/acquire at agent scope (cross-XCD coherence for bias vectors).
__device__ inline void gridBarrier(int* cnt, int* gen) {
  __syncthreads();
  if (threadIdx.x == 0) {
    int g = __hip_atomic_load(gen, __ATOMIC_RELAXED, __HIP_MEMORY_SCOPE_AGENT);
    __threadfence();                       // release all prior writes
    int a = __hip_atomic_fetch_add(cnt, 1, __ATOMIC_RELAXED, __HIP_MEMORY_SCOPE_AGENT);
    if (a == NBLK - 1) {
      __hip_atomic_store(cnt, 0, __ATOMIC_RELAXED, __HIP_MEMORY_SCOPE_AGENT);
      __hip_atomic_store(gen, g + 1, __ATOMIC_RELAXED, __HIP_MEMORY_SCOPE_AGENT);
    } else {
      while (__hip_atomic_load(gen, __ATOMIC_RELAXED, __HIP_MEMORY_SCOPE_AGENT) == g)
        __builtin_amdgcn_s_sleep(2);
    }
    __threadfence();                       // acquire: drop stale cached lines
  }
  __syncthreads();
}

// Pack x/y into MFMA-fragment-major fp16 tiles: frag[tile][g][r][8] (1 KB/tile);
// lane l loads its fragment for tile T at byte T*1024 + l*16 (coalesced 1 KB).
// x pre-scaled by 20/ln2 -> MFMA yields the base-2 LSE cross term directly.
__global__ __launch_bounds__(256) void prep_kernel(const float* __restrict__ x,
                                                   const float* __restrict__ y,
                                                   _Float16* __restrict__ xh,
                                                   _Float16* __restrict__ yh,
                                                   float* __restrict__ x2,
                                                   float* __restrict__ y2,
                                                   float* __restrict__ vb) {
  int t = threadIdx.x;
  int lane = t & 63;
  int g = lane >> 4, r = lane & 15;
  int tileG = blockIdx.x * 4 + (t >> 6);     // 0..1535 (x tiles then y tiles)
  int isY = tileG >= NTILE;
  int tile = isY ? (tileG - NTILE) : tileG;
  const float* src = isY ? y : x;
  int row = tile * 16 + r;
  const float* p = src + (size_t)row * 32 + g * 8;
  float4 v0 = *(const float4*)p;
  float4 v1 = *(const float4*)(p + 4);
  float sq = v0.x * v0.x + v0.y * v0.y + v0.z * v0.z + v0.w * v0.w +
             v1.x * v1.x + v1.y * v1.y + v1.z * v1.z + v1.w * v1.w;
  sq += __shfl_xor(sq, 16, 64);
  sq += __shfl_xor(sq, 32, 64);              // lanes with same r hold the row sum
  float scale = isY ? 1.0f : 20.0f * INV_LN2;
  f16x8 h;
  h[0] = (_Float16)(scale * v0.x); h[1] = (_Float16)(scale * v0.y);
  h[2] = (_Float16)(scale * v0.z); h[3] = (_Float16)(scale * v0.w);
  h[4] = (_Float16)(scale * v1.x); h[5] = (_Float16)(scale * v1.y);
  h[6] = (_Float16)(scale * v1.z); h[7] = (_Float16)(scale * v1.w);
  _Float16* dst = (isY ? yh : xh) + (size_t)tile * 512 + lane * 8;
  *(f16x8*)dst = h;
  if (lane < 16) {
    if (isY) { y2[row] = sq; vb[row] = -10.0f * INV_LN2 * sq; }  // v=0 bias
    else     { x2[row] = sq; }
  }
}

// Persistent Sinkhorn loop. 256 blocks x 512 threads; block owns 48 rows of x
// AND the same 48 rows of y; 8 waves partition the 3072 cols (24 col-tiles each).
// it=0 uses the online-max halfstep (offsets unknown); it>=1 uses the fixed-offset
// fast path: offset_i = prev row LSE, derived EXACTLY from the previous potential
// (L2_prev = 10/ln2*(0.1*lmn + nrm_i - pot_prev_i)); folded into the MFMA C
// operand, so the inner loop is 1 exp2 + 1 add per element, branch-free.
// Update simplifies to pot_new = pot_prev - 0.1*ln2*log2(S_residual).
__global__ __launch_bounds__(512, 2) void sinkhorn_kernel(
    const _Float16* __restrict__ xh, const _Float16* __restrict__ yh,
    float* __restrict__ u, float* __restrict__ v,
    float* __restrict__ ub, float* __restrict__ vb,
    const float* __restrict__ x2, const float* __restrict__ y2,
    float* __restrict__ errpart, int* __restrict__ bar, float lmn) {
  int tid = threadIdx.x;
  int lane = tid & 63;
  int w = tid >> 6;
  int rsel = lane & 15;
  int g = lane >> 4;
  int bid = blockIdx.x;
  int b = bid >> 6;                          // 64 blocks per batch
  int tile0 = bid * 3;
  int gr0 = bid * RPB;
  // A-fragments for both phases: loaded ONCE, live in registers for 50 iters.
  f16x8 xfr[3], yfr[3];
#pragma unroll
  for (int rt = 0; rt < 3; ++rt) {
    xfr[rt] = *(const f16x8*)(xh + (size_t)(tile0 + rt) * 512 + lane * 8);
    yfr[rt] = *(const f16x8*)(yh + (size_t)(tile0 + rt) * 512 + lane * 8);
  }
  size_t jbase = ((size_t)(b * TPB + w * CTW)) * 512 + lane * 8;
  const _Float16* BxP = xh + jbase;
  const _Float16* ByP = yh + jbase;
  int biasoff = b * P + w * (CTW * 16) + rsel;

  __shared__ float lm[8][RPB], ls[8][RPB];
  __shared__ int sdone;

  // ---- iteration-0 halfstep: online max (proven R4 path) ----
  auto halfstep_online = [&](const f16x8* afr, const _Float16* Bp, const float* biasIn,
                             const float* nrm, float* pot, float* biasOut, bool trackErr) {
    const float* biasp = biasIn + biasoff;
    float m[3][4], s[3][4];
#pragma unroll
    for (int rt = 0; rt < 3; ++rt)
#pragma unroll
      for (int r = 0; r < 4; ++r) { m[rt][r] = -1e30f; s[rt][r] = 0.f; }
#pragma unroll 2
    for (int c = 0; c < 6; ++c) {
      f16x8 bfr[4];
      float bb[4];
#pragma unroll
      for (int t4 = 0; t4 < 4; ++t4) {
        bfr[t4] = *(const f16x8*)(Bp + ((size_t)(c * 4 + t4) << 9));
        bb[t4] = biasp[(c * 4 + t4) * 16];
      }
      f32x4 acc[3][4];
#pragma unroll
      for (int rt = 0; rt < 3; ++rt)
#pragma unroll
        for (int t4 = 0; t4 < 4; ++t4) {
          f32x4 ci = {bb[t4], bb[t4], bb[t4], bb[t4]};
          acc[rt][t4] = __builtin_amdgcn_mfma_f32_16x16x32_f16(afr[rt], bfr[t4], ci, 0, 0, 0);
        }
#pragma unroll
      for (int rt = 0; rt < 3; ++rt)
#pragma unroll
        for (int r = 0; r < 4; ++r) {
          float a0 = acc[rt][0][r], a1 = acc[rt][1][r], a2 = acc[rt][2][r], a3 = acc[rt][3][r];
          float cm = fmaxf(fmaxf(a0, a1), fmaxf(a2, a3));
          float nm = fmaxf(m[rt][r], cm);
          s[rt][r] = s[rt][r] * fexp2(m[rt][r] - nm) +
                     fexp2(a0 - nm) + fexp2(a1 - nm) + fexp2(a2 - nm) + fexp2(a3 - nm);
          m[rt][r] = nm;
        }
    }
#pragma unroll
    for (int rt = 0; rt < 3; ++rt)
#pragma unroll
      for (int r = 0; r < 4; ++r) {
#pragma unroll
        for (int o = 1; o < 16; o <<= 1) {
          float om = __shfl_xor(m[rt][r], o, 64);
          float os = __shfl_xor(s[rt][r], o, 64);
          float nm = fmaxf(m[rt][r], om);
          s[rt][r] = s[rt][r] * fexp2(m[rt][r] - nm) + os * fexp2(om - nm);
          m[rt][r] = nm;
        }
      }
    __syncthreads();
    if (rsel == 0) {
#pragma unroll
      for (int rt = 0; rt < 3; ++rt)
#pragma unroll
        for (int r = 0; r < 4; ++r) {
          lm[w][rt * 16 + g * 4 + r] = m[rt][r];
          ls[w][rt * 16 + g * 4 + r] = s[rt][r];
        }
    }
    __syncthreads();
    float e = 0.f;
    if (tid < RPB) {
      float M = lm[0][tid], S = ls[0][tid];
#pragma unroll
      for (int w2 = 1; w2 < 8; ++w2) {
        float om = lm[w2][tid], os = ls[w2][tid];
        float nm = fmaxf(M, om);
        S = S * fexp2(M - nm) + os * fexp2(om - nm);
        M = nm;
      }
      float L2v = M + flog2(S);
      int gi = gr0 + tid;
      float nv = 0.1f * lmn + nrm[gi] - 0.1f * LN2 * L2v;
      if (trackErr) e = fabsf(nv - pot[gi]);
      pot[gi] = nv;
      biasOut[gi] = 10.0f * INV_LN2 * (nv - nrm[gi]);
    }
    if (trackErr && tid < 64) {
      e = waveReduceSum(e);
      if (tid == 0) errpart[bid] = e;
    }
  };

  // ---- it>=1 halfstep: fixed-offset LSE, branch-free, 1 exp2/element ----
  auto halfstep_fast = [&](const f16x8* afr, const _Float16* Bp, const float* biasIn,
                           const float* nrm, float* pot, float* biasOut, bool trackErr) {
    const float* biasp = biasIn + biasoff;
    float off[3][4];                         // prev row LSE (base 2), from prev potential
#pragma unroll
    for (int rt = 0; rt < 3; ++rt)
#pragma unroll
      for (int r = 0; r < 4; ++r) {
        int row = gr0 + rt * 16 + g * 4 + r;
        off[rt][r] = 10.0f * INV_LN2 * (0.1f * lmn + nrm[row] - pot[row]);
      }
    float s[3][4];
#pragma unroll
    for (int rt = 0; rt < 3; ++rt)
#pragma unroll
      for (int r = 0; r < 4; ++r) s[rt][r] = 0.f;
#pragma unroll 2
    for (int c = 0; c < 6; ++c) {
      f16x8 bfr[4];
      float bb[4];
#pragma unroll
      for (int t4 = 0; t4 < 4; ++t4) {
        bfr[t4] = *(const f16x8*)(Bp + ((size_t)(c * 4 + t4) << 9));
        bb[t4] = biasp[(c * 4 + t4) * 16];
      }
      f32x4 acc[3][4];
#pragma unroll
      for (int rt = 0; rt < 3; ++rt)
#pragma unroll
        for (int t4 = 0; t4 < 4; ++t4) {
          f32x4 ci = {bb[t4] - off[rt][0], bb[t4] - off[rt][1],
                      bb[t4] - off[rt][2], bb[t4] - off[rt][3]};
          acc[rt][t4] = __builtin_amdgcn_mfma_f32_16x16x32_f16(afr[rt], bfr[t4], ci, 0, 0, 0);
        }
#pragma unroll
      for (int rt = 0; rt < 3; ++rt)
#pragma unroll
        for (int r = 0; r < 4; ++r)
          s[rt][r] += (fexp2(acc[rt][0][r]) + fexp2(acc[rt][1][r])) +
                      (fexp2(acc[rt][2][r]) + fexp2(acc[rt][3][r]));
    }
    // pure-sum butterfly over the 16-lane col groups
#pragma unroll
    for (int rt = 0; rt < 3; ++rt)
#pragma unroll
      for (int r = 0; r < 4; ++r) {
#pragma unroll
        for (int o = 1; o < 16; o <<= 1)
          s[rt][r] += __shfl_xor(s[rt][r], o, 64);
      }
    __syncthreads();
    if (rsel == 0) {
#pragma unroll
      for (int rt = 0; rt < 3; ++rt)
#pragma unroll
        for (int r = 0; r < 4; ++r) ls[w][rt * 16 + g * 4 + r] = s[rt][r];
    }
    __syncthreads();
    float e = 0.f;
    if (tid < RPB) {
      float S = ls[0][tid];
#pragma unroll
      for (int w2 = 1; w2 < 8; ++w2) S += ls[w2][tid];
      int gi = gr0 + tid;
      float po = pot[gi];
      float nv = po - 0.1f * LN2 * flog2(S);   // pot_new = pot_prev - eps*ln(S_resid)
      if (trackErr) e = fabsf(nv - po);
      pot[gi] = nv;
      biasOut[gi] = 10.0f * INV_LN2 * (nv - nrm[gi]);
    }
    if (trackErr && tid < 64) {
      e = waveReduceSum(e);
      if (tid == 0) errpart[bid] = e;
    }
  };

  for (int it = 0; it < MAXIT; ++it) {
    if (it == 0) halfstep_online(xfr, ByP, vb, x2, u, ub, true);
    else         halfstep_fast(xfr, ByP, vb, x2, u, ub, true);
    gridBarrier(bar, bar + 1);
    if (bid == 0 && tid < 64) {              // errpart complete after barrier
      float ts = errpart[tid] + errpart[tid + 64] +
                 errpart[tid + 128] + errpart[tid + 192];
      ts = waveReduceSum(ts);
      if (tid == 0)
        __hip_atomic_store(bar + 2, (ts * 0.25f < 0.1f) ? 1 : 0,
                           __ATOMIC_RELAXED, __HIP_MEMORY_SCOPE_AGENT);
    }
    if (it == 0) halfstep_online(yfr, BxP, ub, y2, v, vb, false);
    else         halfstep_fast(yfr, BxP, ub, y2, v, vb, false);
    gridBarrier(bar, bar + 1);
    if (tid == 0)
      sdone = __hip_atomic_load(bar + 2, __ATOMIC_RELAXED, __HIP_MEMORY_SCOPE_AGENT);
    __syncthreads();
    if (sdone) break;                        // freeze u,v (matches reference)
  }
}

// Single fused epilogue: exact fp32 C, pi = exp((u+v-C)*10), cost partials.
__global__ __launch_bounds__(256) void final_kernel(const float* __restrict__ x,
                                                    const float* __restrict__ y,
                                                    const float* __restrict__ x2,
                                                    const float* __restrict__ y2,
                                                    const float* __restrict__ u,
                                                    const float* __restrict__ v,
                                                    float* __restrict__ C,
                                                    float* __restrict__ pi,
                                                    float* __restrict__ costpart) {
  __shared__ float xs[64][33];
  __shared__ float ys[64][33];
  int t = threadIdx.x;
  int b = blockIdx.z;
  int i0 = blockIdx.x * 64;
  int j0 = blockIdx.y * 64;
  const float4* xg = (const float4*)(x + ((size_t)b * P + i0) * 32);
  const float4* yg = (const float4*)(y + ((size_t)b * P + j0) * 32);
#pragma unroll
  for (int k = 0; k < 2; ++k) {
    int f4 = t + k * 256;
    int row = f4 >> 3;
    int col = (f4 & 7) << 2;
    float4 xv = xg[f4];
    xs[row][col] = xv.x; xs[row][col + 1] = xv.y; xs[row][col + 2] = xv.z; xs[row][col + 3] = xv.w;
    float4 yv = yg[f4];
    ys[row][col] = yv.x; ys[row][col + 1] = yv.y; ys[row][col + 2] = yv.z; ys[row][col + 3] = yv.w;
  }
  __syncthreads();
  int ti = t >> 4, tj = t & 15;
  int ib = ti * 4, jb = tj * 4;
  float acc[4][4];
#pragma unroll
  for (int a = 0; a < 4; ++a)
#pragma unroll
    for (int bb = 0; bb < 4; ++bb) acc[a][bb] = 0.f;
#pragma unroll 8
  for (int k = 0; k < 32; ++k) {
    float xa[4], yb[4];
#pragma unroll
    for (int a = 0; a < 4; ++a) xa[a] = xs[ib + a][k];
#pragma unroll
    for (int bb = 0; bb < 4; ++bb) yb[bb] = ys[jb + bb][k];
#pragma unroll
    for (int a = 0; a < 4; ++a)
#pragma unroll
      for (int bb = 0; bb < 4; ++bb) acc[a][bb] = fmaf(xa[a], yb[bb], acc[a][bb]);
  }
  float y2r[4], vr[4];
#pragma unroll
  for (int bb = 0; bb < 4; ++bb) {
    y2r[bb] = y2[b * P + j0 + jb + bb];
    vr[bb] = v[b * P + j0 + jb + bb];
  }
  float costacc = 0.f;
#pragma unroll
  for (int a = 0; a < 4; ++a) {
    int gi = b * P + i0 + ib + a;
    float x2r = x2[gi];
    float ur = u[gi];
    float4 co, po;
    co.x = x2r + y2r[0] - 2.f * acc[a][0];
    co.y = x2r + y2r[1] - 2.f * acc[a][1];
    co.z = x2r + y2r[2] - 2.f * acc[a][2];
    co.w = x2r + y2r[3] - 2.f * acc[a][3];
    po.x = __expf((ur + vr[0] - co.x) * 10.f);
    po.y = __expf((ur + vr[1] - co.y) * 10.f);
    po.z = __expf((ur + vr[2] - co.z) * 10.f);
    po.w = __expf((ur + vr[3] - co.w) * 10.f);
    costacc += po.x * co.x + po.y * co.y + po.z * co.z + po.w * co.w;
    float* crow = C + (size_t)gi * P + j0;
    ((float4*)crow)[tj] = co;
    float* prow = pi + (size_t)gi * P + j0;
    ((float4*)prow)[tj] = po;
  }
  costacc = waveReduceSum(costacc);
  __shared__ float red[4];
  if ((t & 63) == 0) red[t >> 6] = costacc;
  __syncthreads();
  if (t == 0)
    costpart[((size_t)b * 48 + blockIdx.y) * 48 + blockIdx.x] =
        red[0] + red[1] + red[2] + red[3];
}

__global__ __launch_bounds__(256) void cost_kernel(const float* __restrict__ costpart,
                                                   float* __restrict__ cost) {
  __shared__ float red[4];
  int t = threadIdx.x;
  for (int b = 0; b < BATCH; ++b) {
    float loc = 0.f;
    for (int idx = t; idx < 2304; idx += 256) loc += costpart[b * 2304 + idx];
    loc = waveReduceSum(loc);
    if ((t & 63) == 0) red[t >> 6] = loc;
    __syncthreads();
    if (t == 0) cost[b] = red[0] + red[1] + red[2] + red[3];
    __syncthreads();
  }
}

extern "C" void kernel_launch(void* const* d_in, const int* in_sizes, int n_in,
                              void* d_out, int out_size, void* d_ws, size_t ws_size,
                              hipStream_t stream) {
  (void)in_sizes; (void)n_in; (void)out_size; (void)ws_size;
  const float* x = (const float*)d_in[0];
  const float* y = (const float*)d_in[1];
  float* out = (float*)d_out;
  float* cost = out;                          // [4]
  float* pi = out + 4;                        // [4*3072*3072]
  float* C = pi + (size_t)BATCH * P * P;      // [4*3072*3072]

  float* u = (float*)d_ws;                    // 12288
  int* bar = (int*)(u + NROW);                // 64 ints: cnt, gen, done
  float* v = (float*)(bar + 64);              // 12288
  float* ub = v + NROW;                       // 12288  (10/ln2*(u - x2))
  float* vb = ub + NROW;                      // 12288  (10/ln2*(v - y2))
  float* x2 = vb + NROW;                      // 12288
  float* y2 = x2 + NROW;                      // 12288
  float* errpart = y2 + NROW;                 // 256
  float* costpart = errpart + NBLK;           // 9216

  // fp16 fragment-packed scratch lives in the C output region (written last)
  _Float16* xh = (_Float16*)C;                // [768 tiles][1 KB] = 20/ln2 * x
  _Float16* yh = xh + (size_t)NROW * 32;      // [768 tiles][1 KB] = y

  // zero u + barrier state (harness poisons ws each call)
  hipMemsetAsync(d_ws, 0, (size_t)NROW * sizeof(float) + 64 * sizeof(int), stream);

  float lmn = logf(1.0f / 3072.0f + 1e-8f);   // log_mu == log_nu

  prep_kernel<<<384, 256, 0, stream>>>(x, y, xh, yh, x2, y2, vb);
  sinkhorn_kernel<<<NBLK, 512, 0, stream>>>(xh, yh, u, v, ub, vb, x2, y2,
                                            errpart, bar, lmn);
  final_kernel<<<dim3(48, 48, 4), 256, 0, stream>>>(x, y, x2, y2, u, v, C, pi, costpart);
  cost_kernel<<<1, 256, 0, stream>>>(costpart, cost);
}

// Round 6
// 2781.280 us; speedup vs baseline: 1.3270x; 1.1291x over previous
//
#include <hip/hip_runtime.h>
#include <math.h>

#define BATCH 4
#define P 3072
#define NROW (BATCH * P)        // 12288
#define NTILE (NROW / 16)       // 768 row-tiles of 16 rows
#define TPB (P / 16)            // 192 tiles per batch
#define MAXIT 50
#define NBLK 256                // persistent blocks, 1 per CU
#define RPB 48                  // rows per block (3 row-tiles)
#define CTW 24                  // col-tiles per wave (8 waves x 24 x 16 = 3072 cols)

#define LN2 0.69314718055994531f
#define INV_LN2 1.44269504088896341f

typedef _Float16 f16x8 __attribute__((ext_vector_type(8)));
typedef float f32x4 __attribute__((ext_vector_type(4)));

__device__ inline float waveReduceSum(float v) {
#pragma unroll
  for (int off = 32; off > 0; off >>= 1) v += __shfl_xor(v, off, 64);
  return v;
}
__device__ inline float fexp2(float x) { return __builtin_amdgcn_exp2f(x); }
__device__ inline float flog2(float x) { return __builtin_amdgcn_logf(x); }  // v_log_f32 = log2

// Agent-coherent (sc1) scalar accessors: bypass L2, read/write at the L3
// coherence point. Only the bias vectors / errpart / done flag cross blocks,
// so ONLY they pay the coherence cost; everything else stays L2-cached.
__device__ inline float cohLoad(const float* p) {
  return __hip_atomic_load(p, __ATOMIC_RELAXED, __HIP_MEMORY_SCOPE_AGENT);
}
__device__ inline void cohStore(float* p, float val) {
  __hip_atomic_store(p, val, __ATOMIC_RELAXED, __HIP_MEMORY_SCOPE_AGENT);
}
__device__ inline int cohLoadI(const int* p) {
  return __hip_atomic_load(p, __ATOMIC_RELAXED, __HIP_MEMORY_SCOPE_AGENT);
}
__device__ inline void cohStoreI(int* p, int val) {
  __hip_atomic_store(p, val, __ATOMIC_RELAXED, __HIP_MEMORY_SCOPE_AGENT);
}

// Fence-free grid barrier, two-level arrival tree (16 groups x 16 blocks),
// monotonic counters (no reset race). NO buffer_wbl2 / buffer_inv: cross-block
// data uses sc1 accessors, and __syncthreads() drains vmcnt before arrival
// (compiler emits s_waitcnt vmcnt(0) before s_barrier), so sc1 stores are at
// the coherence point before the generation flip.
// bar layout (ints): [g*16] 16 group counters (64 B apart), [256] root, [272] gen.
__device__ inline void gridBarrier(int* bar, int target) {
  __syncthreads();                         // drains vmcnt: sc1 stores visible
  if (threadIdx.x == 0) {
    __builtin_amdgcn_sched_barrier(0);
    int g = blockIdx.x >> 4;
    int old = __hip_atomic_fetch_add(&bar[g * 16], 1, __ATOMIC_RELAXED,
                                     __HIP_MEMORY_SCOPE_AGENT);
    if ((old & 15) == 15) {                // last of this group, this barrier
      int r = __hip_atomic_fetch_add(&bar[256], 1, __ATOMIC_RELAXED,
                                     __HIP_MEMORY_SCOPE_AGENT);
      if ((r & 15) == 15)                  // last group overall
        cohStoreI(&bar[272], target);
    }
    while (cohLoadI(&bar[272]) < target) __builtin_amdgcn_s_sleep(1);
    __builtin_amdgcn_sched_barrier(0);
  }
  __syncthreads();
}

// Pack x/y into MFMA-fragment-major fp16 tiles: frag[tile][g][r][8] (1 KB/tile);
// lane l loads its fragment for tile T at byte T*1024 + l*16 (coalesced 1 KB).
// x pre-scaled by 20/ln2 -> MFMA yields the base-2 LSE cross term directly.
__global__ __launch_bounds__(256) void prep_kernel(const float* __restrict__ x,
                                                   const float* __restrict__ y,
                                                   _Float16* __restrict__ xh,
                                                   _Float16* __restrict__ yh,
                                                   float* __restrict__ x2,
                                                   float* __restrict__ y2,
                                                   float* __restrict__ vb) {
  int t = threadIdx.x;
  int lane = t & 63;
  int g = lane >> 4, r = lane & 15;
  int tileG = blockIdx.x * 4 + (t >> 6);     // 0..1535 (x tiles then y tiles)
  int isY = tileG >= NTILE;
  int tile = isY ? (tileG - NTILE) : tileG;
  const float* src = isY ? y : x;
  int row = tile * 16 + r;
  const float* p = src + (size_t)row * 32 + g * 8;
  float4 v0 = *(const float4*)p;
  float4 v1 = *(const float4*)(p + 4);
  float sq = v0.x * v0.x + v0.y * v0.y + v0.z * v0.z + v0.w * v0.w +
             v1.x * v1.x + v1.y * v1.y + v1.z * v1.z + v1.w * v1.w;
  sq += __shfl_xor(sq, 16, 64);
  sq += __shfl_xor(sq, 32, 64);              // lanes with same r hold the row sum
  float scale = isY ? 1.0f : 20.0f * INV_LN2;
  f16x8 h;
  h[0] = (_Float16)(scale * v0.x); h[1] = (_Float16)(scale * v0.y);
  h[2] = (_Float16)(scale * v0.z); h[3] = (_Float16)(scale * v0.w);
  h[4] = (_Float16)(scale * v1.x); h[5] = (_Float16)(scale * v1.y);
  h[6] = (_Float16)(scale * v1.z); h[7] = (_Float16)(scale * v1.w);
  _Float16* dst = (isY ? yh : xh) + (size_t)tile * 512 + lane * 8;
  *(f16x8*)dst = h;
  if (lane < 16) {
    if (isY) { y2[row] = sq; vb[row] = -10.0f * INV_LN2 * sq; }  // v=0 bias
    else     { x2[row] = sq; }
  }
}

// Persistent Sinkhorn loop. 256 blocks x 512 threads; block owns 48 rows of x
// AND the same 48 rows of y; 8 waves partition the 3072 cols (24 col-tiles each).
// it=0: online-max halfstep. it>=1: fixed-offset fast path (offset = prev row
// LSE derived from the previous potential, folded into the MFMA C operand;
// 1 exp2 + 1 add per element, branch-free; update pot -= 0.1*ln2*log2(S)).
// Cross-block data (bias in/out, errpart, done) uses sc1 coherent accessors;
// fragments and potentials stay L2-cached across all iterations.
__global__ __launch_bounds__(512, 2) void sinkhorn_kernel(
    const _Float16* __restrict__ xh, const _Float16* __restrict__ yh,
    float* __restrict__ u, float* __restrict__ v,
    float* __restrict__ ub, float* __restrict__ vb,
    const float* __restrict__ x2, const float* __restrict__ y2,
    float* __restrict__ errpart, int* __restrict__ bar, float lmn) {
  int tid = threadIdx.x;
  int lane = tid & 63;
  int w = tid >> 6;
  int rsel = lane & 15;
  int g = lane >> 4;
  int bid = blockIdx.x;
  int b = bid >> 6;                          // 64 blocks per batch
  int tile0 = bid * 3;
  int gr0 = bid * RPB;
  // A-fragments for both phases: loaded ONCE, live in registers for 50 iters.
  f16x8 xfr[3], yfr[3];
#pragma unroll
  for (int rt = 0; rt < 3; ++rt) {
    xfr[rt] = *(const f16x8*)(xh + (size_t)(tile0 + rt) * 512 + lane * 8);
    yfr[rt] = *(const f16x8*)(yh + (size_t)(tile0 + rt) * 512 + lane * 8);
  }
  size_t jbase = ((size_t)(b * TPB + w * CTW)) * 512 + lane * 8;
  const _Float16* BxP = xh + jbase;
  const _Float16* ByP = yh + jbase;
  int biasoff = b * P + w * (CTW * 16) + rsel;

  __shared__ float lm[8][RPB], ls[8][RPB];
  __shared__ int sdone;

  // ---- iteration-0 halfstep: online max (proven path) ----
  auto halfstep_online = [&](const f16x8* afr, const _Float16* Bp, const float* biasIn,
                             const float* nrm, float* pot, float* biasOut, bool trackErr) {
    const float* biasp = biasIn + biasoff;
    float m[3][4], s[3][4];
#pragma unroll
    for (int rt = 0; rt < 3; ++rt)
#pragma unroll
      for (int r = 0; r < 4; ++r) { m[rt][r] = -1e30f; s[rt][r] = 0.f; }
#pragma unroll 2
    for (int c = 0; c < 6; ++c) {
      f16x8 bfr[4];
      float bb[4];
#pragma unroll
      for (int t4 = 0; t4 < 4; ++t4) {
        bfr[t4] = *(const f16x8*)(Bp + ((size_t)(c * 4 + t4) << 9));
        bb[t4] = cohLoad(&biasp[(c * 4 + t4) * 16]);
      }
      f32x4 acc[3][4];
#pragma unroll
      for (int rt = 0; rt < 3; ++rt)
#pragma unroll
        for (int t4 = 0; t4 < 4; ++t4) {
          f32x4 ci = {bb[t4], bb[t4], bb[t4], bb[t4]};
          acc[rt][t4] = __builtin_amdgcn_mfma_f32_16x16x32_f16(afr[rt], bfr[t4], ci, 0, 0, 0);
        }
#pragma unroll
      for (int rt = 0; rt < 3; ++rt)
#pragma unroll
        for (int r = 0; r < 4; ++r) {
          float a0 = acc[rt][0][r], a1 = acc[rt][1][r], a2 = acc[rt][2][r], a3 = acc[rt][3][r];
          float cm = fmaxf(fmaxf(a0, a1), fmaxf(a2, a3));
          float nm = fmaxf(m[rt][r], cm);
          s[rt][r] = s[rt][r] * fexp2(m[rt][r] - nm) +
                     fexp2(a0 - nm) + fexp2(a1 - nm) + fexp2(a2 - nm) + fexp2(a3 - nm);
          m[rt][r] = nm;
        }
    }
#pragma unroll
    for (int rt = 0; rt < 3; ++rt)
#pragma unroll
      for (int r = 0; r < 4; ++r) {
#pragma unroll
        for (int o = 1; o < 16; o <<= 1) {
          float om = __shfl_xor(m[rt][r], o, 64);
          float os = __shfl_xor(s[rt][r], o, 64);
          float nm = fmaxf(m[rt][r], om);
          s[rt][r] = s[rt][r] * fexp2(m[rt][r] - nm) + os * fexp2(om - nm);
          m[rt][r] = nm;
        }
      }
    __syncthreads();
    if (rsel == 0) {
#pragma unroll
      for (int rt = 0; rt < 3; ++rt)
#pragma unroll
        for (int r = 0; r < 4; ++r) {
          lm[w][rt * 16 + g * 4 + r] = m[rt][r];
          ls[w][rt * 16 + g * 4 + r] = s[rt][r];
        }
    }
    __syncthreads();
    float e = 0.f;
    if (tid < RPB) {
      float M = lm[0][tid], S = ls[0][tid];
#pragma unroll
      for (int w2 = 1; w2 < 8; ++w2) {
        float om = lm[w2][tid], os = ls[w2][tid];
        float nm = fmaxf(M, om);
        S = S * fexp2(M - nm) + os * fexp2(om - nm);
        M = nm;
      }
      float L2v = M + flog2(S);
      int gi = gr0 + tid;
      float nv = 0.1f * lmn + nrm[gi] - 0.1f * LN2 * L2v;
      if (trackErr) e = fabsf(nv - pot[gi]);
      pot[gi] = nv;
      cohStore(&biasOut[gi], 10.0f * INV_LN2 * (nv - nrm[gi]));
    }
    if (trackErr && tid < 64) {
      e = waveReduceSum(e);
      if (tid == 0) cohStore(&errpart[bid], e);
    }
  };

  // ---- it>=1 halfstep: fixed-offset LSE, branch-free, 1 exp2/element ----
  auto halfstep_fast = [&](const f16x8* afr, const _Float16* Bp, const float* biasIn,
                           const float* nrm, float* pot, float* biasOut, bool trackErr) {
    const float* biasp = biasIn + biasoff;
    float off[3][4];                         // prev row LSE (base 2), from prev potential
#pragma unroll
    for (int rt = 0; rt < 3; ++rt)
#pragma unroll
      for (int r = 0; r < 4; ++r) {
        int row = gr0 + rt * 16 + g * 4 + r;
        off[rt][r] = 10.0f * INV_LN2 * (0.1f * lmn + nrm[row] - pot[row]);
      }
    // hoist all 24 bias loads (sc1, ~L3 latency) so they overlap the MFMA/exp2
    float bb[24];
#pragma unroll
    for (int c = 0; c < 24; ++c) bb[c] = cohLoad(&biasp[c * 16]);
    float s[3][4];
#pragma unroll
    for (int rt = 0; rt < 3; ++rt)
#pragma unroll
      for (int r = 0; r < 4; ++r) s[rt][r] = 0.f;
#pragma unroll                               // FULL unroll: bb[] stays in registers
    for (int c = 0; c < 6; ++c) {
      f16x8 bfr[4];
#pragma unroll
      for (int t4 = 0; t4 < 4; ++t4)
        bfr[t4] = *(const f16x8*)(Bp + ((size_t)(c * 4 + t4) << 9));
      f32x4 acc[3][4];
#pragma unroll
      for (int rt = 0; rt < 3; ++rt)
#pragma unroll
        for (int t4 = 0; t4 < 4; ++t4) {
          float bv = bb[c * 4 + t4];
          f32x4 ci = {bv - off[rt][0], bv - off[rt][1],
                      bv - off[rt][2], bv - off[rt][3]};
          acc[rt][t4] = __builtin_amdgcn_mfma_f32_16x16x32_f16(afr[rt], bfr[t4], ci, 0, 0, 0);
        }
#pragma unroll
      for (int rt = 0; rt < 3; ++rt)
#pragma unroll
        for (int r = 0; r < 4; ++r)
          s[rt][r] += (fexp2(acc[rt][0][r]) + fexp2(acc[rt][1][r])) +
                      (fexp2(acc[rt][2][r]) + fexp2(acc[rt][3][r]));
    }
    // pure-sum butterfly over the 16-lane col groups
#pragma unroll
    for (int rt = 0; rt < 3; ++rt)
#pragma unroll
      for (int r = 0; r < 4; ++r) {
#pragma unroll
        for (int o = 1; o < 16; o <<= 1)
          s[rt][r] += __shfl_xor(s[rt][r], o, 64);
      }
    __syncthreads();
    if (rsel == 0) {
#pragma unroll
      for (int rt = 0; rt < 3; ++rt)
#pragma unroll
        for (int r = 0; r < 4; ++r) ls[w][rt * 16 + g * 4 + r] = s[rt][r];
    }
    __syncthreads();
    float e = 0.f;
    if (tid < RPB) {
      float S = ls[0][tid];
#pragma unroll
      for (int w2 = 1; w2 < 8; ++w2) S += ls[w2][tid];
      int gi = gr0 + tid;
      float po = pot[gi];
      float nv = po - 0.1f * LN2 * flog2(S);   // pot_new = pot_prev - eps*ln(S_resid)
      if (trackErr) e = fabsf(nv - po);
      pot[gi] = nv;
      cohStore(&biasOut[gi], 10.0f * INV_LN2 * (nv - nrm[gi]));
    }
    if (trackErr && tid < 64) {
      e = waveReduceSum(e);
      if (tid == 0) cohStore(&errpart[bid], e);
    }
  };

  int ep = 0;
  for (int it = 0; it < MAXIT; ++it) {
    if (it == 0) halfstep_online(xfr, ByP, vb, x2, u, ub, true);
    else         halfstep_fast(xfr, ByP, vb, x2, u, ub, true);
    gridBarrier(bar, ++ep);
    if (bid == 0 && tid < 64) {              // errpart complete after barrier
      float ts = cohLoad(&errpart[tid]) + cohLoad(&errpart[tid + 64]) +
                 cohLoad(&errpart[tid + 128]) + cohLoad(&errpart[tid + 192]);
      ts = waveReduceSum(ts);
      if (tid == 0) cohStoreI(&bar[288], (ts * 0.25f < 0.1f) ? 1 : 0);
    }
    if (it == 0) halfstep_online(yfr, BxP, ub, y2, v, vb, false);
    else         halfstep_fast(yfr, BxP, ub, y2, v, vb, false);
    gridBarrier(bar, ++ep);
    if (tid == 0) sdone = cohLoadI(&bar[288]);
    __syncthreads();
    if (sdone) break;                        // freeze u,v (matches reference)
  }
}

// Single fused epilogue: exact fp32 C, pi = exp((u+v-C)*10), cost partials.
__global__ __launch_bounds__(256) void final_kernel(const float* __restrict__ x,
                                                    const float* __restrict__ y,
                                                    const float* __restrict__ x2,
                                                    const float* __restrict__ y2,
                                                    const float* __restrict__ u,
                                                    const float* __restrict__ v,
                                                    float* __restrict__ C,
                                                    float* __restrict__ pi,
                                                    float* __restrict__ costpart) {
  __shared__ float xs[64][33];
  __shared__ float ys[64][33];
  int t = threadIdx.x;
  int b = blockIdx.z;
  int i0 = blockIdx.x * 64;
  int j0 = blockIdx.y * 64;
  const float4* xg = (const float4*)(x + ((size_t)b * P + i0) * 32);
  const float4* yg = (const float4*)(y + ((size_t)b * P + j0) * 32);
#pragma unroll
  for (int k = 0; k < 2; ++k) {
    int f4 = t + k * 256;
    int row = f4 >> 3;
    int col = (f4 & 7) << 2;
    float4 xv = xg[f4];
    xs[row][col] = xv.x; xs[row][col + 1] = xv.y; xs[row][col + 2] = xv.z; xs[row][col + 3] = xv.w;
    float4 yv = yg[f4];
    ys[row][col] = yv.x; ys[row][col + 1] = yv.y; ys[row][col + 2] = yv.z; ys[row][col + 3] = yv.w;
  }
  __syncthreads();
  int ti = t >> 4, tj = t & 15;
  int ib = ti * 4, jb = tj * 4;
  float acc[4][4];
#pragma unroll
  for (int a = 0; a < 4; ++a)
#pragma unroll
    for (int bb = 0; bb < 4; ++bb) acc[a][bb] = 0.f;
#pragma unroll 8
  for (int k = 0; k < 32; ++k) {
    float xa[4], yb[4];
#pragma unroll
    for (int a = 0; a < 4; ++a) xa[a] = xs[ib + a][k];
#pragma unroll
    for (int bb = 0; bb < 4; ++bb) yb[bb] = ys[jb + bb][k];
#pragma unroll
    for (int a = 0; a < 4; ++a)
#pragma unroll
      for (int bb = 0; bb < 4; ++bb) acc[a][bb] = fmaf(xa[a], yb[bb], acc[a][bb]);
  }
  float y2r[4], vr[4];
#pragma unroll
  for (int bb = 0; bb < 4; ++bb) {
    y2r[bb] = y2[b * P + j0 + jb + bb];
    vr[bb] = v[b * P + j0 + jb + bb];
  }
  float costacc = 0.f;
#pragma unroll
  for (int a = 0; a < 4; ++a) {
    int gi = b * P + i0 + ib + a;
    float x2r = x2[gi];
    float ur = u[gi];
    float4 co, po;
    co.x = x2r + y2r[0] - 2.f * acc[a][0];
    co.y = x2r + y2r[1] - 2.f * acc[a][1];
    co.z = x2r + y2r[2] - 2.f * acc[a][2];
    co.w = x2r + y2r[3] - 2.f * acc[a][3];
    po.x = __expf((ur + vr[0] - co.x) * 10.f);
    po.y = __expf((ur + vr[1] - co.y) * 10.f);
    po.z = __expf((ur + vr[2] - co.z) * 10.f);
    po.w = __expf((ur + vr[3] - co.w) * 10.f);
    costacc += po.x * co.x + po.y * co.y + po.z * co.z + po.w * co.w;
    float* crow = C + (size_t)gi * P + j0;
    ((float4*)crow)[tj] = co;
    float* prow = pi + (size_t)gi * P + j0;
    ((float4*)prow)[tj] = po;
  }
  costacc = waveReduceSum(costacc);
  __shared__ float red[4];
  if ((t & 63) == 0) red[t >> 6] = costacc;
  __syncthreads();
  if (t == 0)
    costpart[((size_t)b * 48 + blockIdx.y) * 48 + blockIdx.x] =
        red[0] + red[1] + red[2] + red[3];
}

__global__ __launch_bounds__(256) void cost_kernel(const float* __restrict__ costpart,
                                                   float* __restrict__ cost) {
  __shared__ float red[4];
  int t = threadIdx.x;
  for (int b = 0; b < BATCH; ++b) {
    float loc = 0.f;
    for (int idx = t; idx < 2304; idx += 256) loc += costpart[b * 2304 + idx];
    loc = waveReduceSum(loc);
    if ((t & 63) == 0) red[t >> 6] = loc;
    __syncthreads();
    if (t == 0) cost[b] = red[0] + red[1] + red[2] + red[3];
    __syncthreads();
  }
}

extern "C" void kernel_launch(void* const* d_in, const int* in_sizes, int n_in,
                              void* d_out, int out_size, void* d_ws, size_t ws_size,
                              hipStream_t stream) {
  (void)in_sizes; (void)n_in; (void)out_size; (void)ws_size;
  const float* x = (const float*)d_in[0];
  const float* y = (const float*)d_in[1];
  float* out = (float*)d_out;
  float* cost = out;                          // [4]
  float* pi = out + 4;                        // [4*3072*3072]
  float* C = pi + (size_t)BATCH * P * P;      // [4*3072*3072]

  float* u = (float*)d_ws;                    // 12288
  int* bar = (int*)(u + NROW);                // 512 ints: tree counters/gen/done
  float* v = (float*)(bar + 512);             // 12288
  float* ub = v + NROW;                       // 12288  (10/ln2*(u - x2))
  float* vb = ub + NROW;                      // 12288  (10/ln2*(v - y2))
  float* x2 = vb + NROW;                      // 12288
  float* y2 = x2 + NROW;                      // 12288
  float* errpart = y2 + NROW;                 // 256
  float* costpart = errpart + NBLK;           // 9216

  // fp16 fragment-packed scratch lives in the C output region (written last)
  _Float16* xh = (_Float16*)C;                // [768 tiles][1 KB] = 20/ln2 * x
  _Float16* yh = xh + (size_t)NROW * 32;      // [768 tiles][1 KB] = y

  // zero u + barrier state (harness poisons ws each call)
  hipMemsetAsync(d_ws, 0, (size_t)NROW * sizeof(float) + 512 * sizeof(int), stream);

  float lmn = logf(1.0f / 3072.0f + 1e-8f);   // log_mu == log_nu

  prep_kernel<<<384, 256, 0, stream>>>(x, y, xh, yh, x2, y2, vb);
  sinkhorn_kernel<<<NBLK, 512, 0, stream>>>(xh, yh, u, v, ub, vb, x2, y2,
                                            errpart, bar, lmn);
  final_kernel<<<dim3(48, 48, 4), 256, 0, stream>>>(x, y, x2, y2, u, v, C, pi, costpart);
  cost_kernel<<<1, 256, 0, stream>>>(costpart, cost);
}

// Round 7
// 1569.795 us; speedup vs baseline: 2.3511x; 1.7717x over previous
//
#include <hip/hip_runtime.h>
#include <math.h>

#define BATCH 4
#define P 3072
#define NROW (BATCH * P)        // 12288
#define NTILE (NROW / 16)       // 768 row-tiles of 16 rows
#define TPB (P / 16)            // 192 tiles per batch
#define MAXIT 50
#define NBLK 256                // persistent blocks, 1 per CU
#define RPB 48                  // rows per block (3 row-tiles)
#define CTW 24                  // col-tiles per wave (8 waves x 24 x 16 = 3072 cols)

#define LN2 0.69314718055994531f
#define INV_LN2 1.44269504088896341f

typedef _Float16 f16x8 __attribute__((ext_vector_type(8)));
typedef float f32x4 __attribute__((ext_vector_type(4)));

__device__ inline float waveReduceSum(float v) {
#pragma unroll
  for (int off = 32; off > 0; off >>= 1) v += __shfl_xor(v, off, 64);
  return v;
}
__device__ inline float fexp2(float x) { return __builtin_amdgcn_exp2f(x); }
__device__ inline float flog2(float x) { return __builtin_amdgcn_logf(x); }  // v_log_f32 = log2

// Agent-coherent (sc1) scalar accessors: bypass L2, read/write at the L3
// coherence point. Only cross-block data (bias vectors, errpart, done flag)
// pays the coherence cost; fragments/potentials stay L2-cached.
__device__ inline float cohLoad(const float* p) {
  return __hip_atomic_load(p, __ATOMIC_RELAXED, __HIP_MEMORY_SCOPE_AGENT);
}
__device__ inline void cohStore(float* p, float val) {
  __hip_atomic_store(p, val, __ATOMIC_RELAXED, __HIP_MEMORY_SCOPE_AGENT);
}
__device__ inline int cohLoadI(const int* p) {
  return __hip_atomic_load(p, __ATOMIC_RELAXED, __HIP_MEMORY_SCOPE_AGENT);
}
__device__ inline void cohStoreI(int* p, int val) {
  __hip_atomic_store(p, val, __ATOMIC_RELAXED, __HIP_MEMORY_SCOPE_AGENT);
}

// Fence-free grid barrier, two-level arrival tree (16 groups x 16 blocks),
// monotonic counters. No buffer_wbl2/buffer_inv: cross-block data uses sc1
// accessors; __syncthreads() drains vmcnt before arrival so sc1 stores are
// at the coherence point before the generation flip.
// bar ints: [g*16] 16 group counters (64 B apart), [256] root, [272] gen, [288] done.
__device__ inline void gridBarrier(int* bar, int target) {
  __syncthreads();                         // drains vmcnt: sc1 stores visible
  if (threadIdx.x == 0) {
    __builtin_amdgcn_sched_barrier(0);
    int g = blockIdx.x >> 4;
    int old = __hip_atomic_fetch_add(&bar[g * 16], 1, __ATOMIC_RELAXED,
                                     __HIP_MEMORY_SCOPE_AGENT);
    if ((old & 15) == 15) {                // last of this group, this round
      int r = __hip_atomic_fetch_add(&bar[256], 1, __ATOMIC_RELAXED,
                                     __HIP_MEMORY_SCOPE_AGENT);
      if ((r & 15) == 15)                  // last group overall
        cohStoreI(&bar[272], target);
    }
    while (cohLoadI(&bar[272]) < target) __builtin_amdgcn_s_sleep(1);
    __builtin_amdgcn_sched_barrier(0);
  }
  __syncthreads();
}

// Pack x/y into MFMA-fragment-major fp16 tiles: frag[tile][g][r][8] (1 KB/tile);
// lane l loads its fragment for tile T at byte T*1024 + l*16 (coalesced 1 KB).
// x pre-scaled by 20/ln2 -> MFMA yields the base-2 LSE cross term directly.
__global__ __launch_bounds__(256) void prep_kernel(const float* __restrict__ x,
                                                   const float* __restrict__ y,
                                                   _Float16* __restrict__ xh,
                                                   _Float16* __restrict__ yh,
                                                   float* __restrict__ x2,
                                                   float* __restrict__ y2,
                                                   float* __restrict__ vb) {
  int t = threadIdx.x;
  int lane = t & 63;
  int g = lane >> 4, r = lane & 15;
  int tileG = blockIdx.x * 4 + (t >> 6);     // 0..1535 (x tiles then y tiles)
  int isY = tileG >= NTILE;
  int tile = isY ? (tileG - NTILE) : tileG;
  const float* src = isY ? y : x;
  int row = tile * 16 + r;
  const float* p = src + (size_t)row * 32 + g * 8;
  float4 v0 = *(const float4*)p;
  float4 v1 = *(const float4*)(p + 4);
  float sq = v0.x * v0.x + v0.y * v0.y + v0.z * v0.z + v0.w * v0.w +
             v1.x * v1.x + v1.y * v1.y + v1.z * v1.z + v1.w * v1.w;
  sq += __shfl_xor(sq, 16, 64);
  sq += __shfl_xor(sq, 32, 64);              // lanes with same r hold the row sum
  float scale = isY ? 1.0f : 20.0f * INV_LN2;
  f16x8 h;
  h[0] = (_Float16)(scale * v0.x); h[1] = (_Float16)(scale * v0.y);
  h[2] = (_Float16)(scale * v0.z); h[3] = (_Float16)(scale * v0.w);
  h[4] = (_Float16)(scale * v1.x); h[5] = (_Float16)(scale * v1.y);
  h[6] = (_Float16)(scale * v1.z); h[7] = (_Float16)(scale * v1.w);
  _Float16* dst = (isY ? yh : xh) + (size_t)tile * 512 + lane * 8;
  *(f16x8*)dst = h;
  if (lane < 16) {
    if (isY) { y2[row] = sq; vb[row] = -10.0f * INV_LN2 * sq; }  // v=0 bias
    else     { x2[row] = sq; }
  }
}

// Persistent Sinkhorn loop. 256 blocks x 512 threads; block owns 48 rows of x
// AND the same 48 rows of y; 8 waves partition the 3072 cols (24 col-tiles each).
// Each halfstep first stages the 12 KB batch-bias vector into LDS via one
// parallel round of sc1 loads (pays the L3 latency ONCE, not per chunk), then
// runs the LSE sweep reading bias from LDS (broadcast, conflict-free).
// it=0: online-max path. it>=1: fixed-offset path (offset = prev row LSE from
// the previous potential, folded into the MFMA C operand; 1 exp2 + 1 add per
// element, branch-free; update pot -= 0.1*ln2*log2(S)). acc consumed per
// row-tile to keep live VGPRs low (R6's bb[24]+full-unroll spilled to scratch:
// 6.6 GB of HBM spill traffic = the whole dispatch time).
__global__ __launch_bounds__(512, 2) void sinkhorn_kernel(
    const _Float16* __restrict__ xh, const _Float16* __restrict__ yh,
    float* __restrict__ u, float* __restrict__ v,
    float* __restrict__ ub, float* __restrict__ vb,
    const float* __restrict__ x2, const float* __restrict__ y2,
    float* __restrict__ errpart, int* __restrict__ bar, float lmn) {
  int tid = threadIdx.x;
  int lane = tid & 63;
  int w = tid >> 6;
  int rsel = lane & 15;
  int g = lane >> 4;
  int bid = blockIdx.x;
  int b = bid >> 6;                          // 64 blocks per batch
  int tile0 = bid * 3;
  int gr0 = bid * RPB;
  // A-fragments for both phases: loaded ONCE, live in registers for 50 iters.
  f16x8 xfr[3], yfr[3];
#pragma unroll
  for (int rt = 0; rt < 3; ++rt) {
    xfr[rt] = *(const f16x8*)(xh + (size_t)(tile0 + rt) * 512 + lane * 8);
    yfr[rt] = *(const f16x8*)(yh + (size_t)(tile0 + rt) * 512 + lane * 8);
  }
  size_t jbase = ((size_t)(b * TPB + w * CTW)) * 512 + lane * 8;
  const _Float16* BxP = xh + jbase;
  const _Float16* ByP = yh + jbase;
  int sboff = w * (CTW * 16) + rsel;         // this wave's bias base in LDS

  __shared__ float sb[P];                    // 12 KB staged bias (this batch)
  __shared__ float lm[8][RPB], ls[8][RPB];
  __shared__ int sdone;

  // stage biasIn[b*P .. +3071] -> sb via 6 coalesced sc1 loads per thread
  auto stageBias = [&](const float* biasIn) {
    const float* bp = biasIn + b * P;
#pragma unroll
    for (int k = 0; k < 6; ++k) sb[tid + k * 512] = cohLoad(&bp[tid + k * 512]);
    __syncthreads();
  };

  // ---- iteration-0 halfstep: online max (proven path) ----
  auto halfstep_online = [&](const f16x8* afr, const _Float16* Bp,
                             const float* nrm, float* pot, float* biasOut, bool trackErr) {
    float m[3][4], s[3][4];
#pragma unroll
    for (int rt = 0; rt < 3; ++rt)
#pragma unroll
      for (int r = 0; r < 4; ++r) { m[rt][r] = -1e30f; s[rt][r] = 0.f; }
#pragma unroll 2
    for (int c = 0; c < 6; ++c) {
      f16x8 bfr[4];
      float bb[4];
#pragma unroll
      for (int t4 = 0; t4 < 4; ++t4) {
        bfr[t4] = *(const f16x8*)(Bp + ((size_t)(c * 4 + t4) << 9));
        bb[t4] = sb[sboff + (c * 4 + t4) * 16];
      }
#pragma unroll
      for (int rt = 0; rt < 3; ++rt) {
        f32x4 acc[4];
#pragma unroll
        for (int t4 = 0; t4 < 4; ++t4) {
          f32x4 ci = {bb[t4], bb[t4], bb[t4], bb[t4]};
          acc[t4] = __builtin_amdgcn_mfma_f32_16x16x32_f16(afr[rt], bfr[t4], ci, 0, 0, 0);
        }
#pragma unroll
        for (int r = 0; r < 4; ++r) {
          float a0 = acc[0][r], a1 = acc[1][r], a2 = acc[2][r], a3 = acc[3][r];
          float cm = fmaxf(fmaxf(a0, a1), fmaxf(a2, a3));
          float nm = fmaxf(m[rt][r], cm);
          s[rt][r] = s[rt][r] * fexp2(m[rt][r] - nm) +
                     fexp2(a0 - nm) + fexp2(a1 - nm) + fexp2(a2 - nm) + fexp2(a3 - nm);
          m[rt][r] = nm;
        }
      }
    }
#pragma unroll
    for (int rt = 0; rt < 3; ++rt)
#pragma unroll
      for (int r = 0; r < 4; ++r) {
#pragma unroll
        for (int o = 1; o < 16; o <<= 1) {
          float om = __shfl_xor(m[rt][r], o, 64);
          float os = __shfl_xor(s[rt][r], o, 64);
          float nm = fmaxf(m[rt][r], om);
          s[rt][r] = s[rt][r] * fexp2(m[rt][r] - nm) + os * fexp2(om - nm);
          m[rt][r] = nm;
        }
      }
    __syncthreads();
    if (rsel == 0) {
#pragma unroll
      for (int rt = 0; rt < 3; ++rt)
#pragma unroll
        for (int r = 0; r < 4; ++r) {
          lm[w][rt * 16 + g * 4 + r] = m[rt][r];
          ls[w][rt * 16 + g * 4 + r] = s[rt][r];
        }
    }
    __syncthreads();
    float e = 0.f;
    if (tid < RPB) {
      float M = lm[0][tid], S = ls[0][tid];
#pragma unroll
      for (int w2 = 1; w2 < 8; ++w2) {
        float om = lm[w2][tid], os = ls[w2][tid];
        float nm = fmaxf(M, om);
        S = S * fexp2(M - nm) + os * fexp2(om - nm);
        M = nm;
      }
      float L2v = M + flog2(S);
      int gi = gr0 + tid;
      float nv = 0.1f * lmn + nrm[gi] - 0.1f * LN2 * L2v;
      if (trackErr) e = fabsf(nv - pot[gi]);
      pot[gi] = nv;
      cohStore(&biasOut[gi], 10.0f * INV_LN2 * (nv - nrm[gi]));
    }
    if (trackErr && tid < 64) {
      e = waveReduceSum(e);
      if (tid == 0) cohStore(&errpart[bid], e);
    }
  };

  // ---- it>=1 halfstep: fixed-offset LSE, branch-free, 1 exp2/element ----
  auto halfstep_fast = [&](const f16x8* afr, const _Float16* Bp,
                           const float* nrm, float* pot, float* biasOut, bool trackErr) {
    float off[3][4];                         // prev row LSE (base 2), from prev potential
#pragma unroll
    for (int rt = 0; rt < 3; ++rt)
#pragma unroll
      for (int r = 0; r < 4; ++r) {
        int row = gr0 + rt * 16 + g * 4 + r;
        off[rt][r] = 10.0f * INV_LN2 * (0.1f * lmn + nrm[row] - pot[row]);
      }
    float s[3][4];
#pragma unroll
    for (int rt = 0; rt < 3; ++rt)
#pragma unroll
      for (int r = 0; r < 4; ++r) s[rt][r] = 0.f;
#pragma unroll 2
    for (int c = 0; c < 6; ++c) {
      f16x8 bfr[4];
      float bb[4];
#pragma unroll
      for (int t4 = 0; t4 < 4; ++t4) {
        bfr[t4] = *(const f16x8*)(Bp + ((size_t)(c * 4 + t4) << 9));
        bb[t4] = sb[sboff + (c * 4 + t4) * 16];
      }
#pragma unroll
      for (int rt = 0; rt < 3; ++rt) {       // consume acc per row-tile: low pressure
        f32x4 acc[4];
#pragma unroll
        for (int t4 = 0; t4 < 4; ++t4) {
          f32x4 ci = {bb[t4] - off[rt][0], bb[t4] - off[rt][1],
                      bb[t4] - off[rt][2], bb[t4] - off[rt][3]};
          acc[t4] = __builtin_amdgcn_mfma_f32_16x16x32_f16(afr[rt], bfr[t4], ci, 0, 0, 0);
        }
#pragma unroll
        for (int r = 0; r < 4; ++r)
          s[rt][r] += (fexp2(acc[0][r]) + fexp2(acc[1][r])) +
                      (fexp2(acc[2][r]) + fexp2(acc[3][r]));
      }
    }
    // pure-sum butterfly over the 16-lane col groups
#pragma unroll
    for (int rt = 0; rt < 3; ++rt)
#pragma unroll
      for (int r = 0; r < 4; ++r) {
#pragma unroll
        for (int o = 1; o < 16; o <<= 1)
          s[rt][r] += __shfl_xor(s[rt][r], o, 64);
      }
    __syncthreads();
    if (rsel == 0) {
#pragma unroll
      for (int rt = 0; rt < 3; ++rt)
#pragma unroll
        for (int r = 0; r < 4; ++r) ls[w][rt * 16 + g * 4 + r] = s[rt][r];
    }
    __syncthreads();
    float e = 0.f;
    if (tid < RPB) {
      float S = ls[0][tid];
#pragma unroll
      for (int w2 = 1; w2 < 8; ++w2) S += ls[w2][tid];
      int gi = gr0 + tid;
      float po = pot[gi];
      float nv = po - 0.1f * LN2 * flog2(S);   // pot_new = pot_prev - eps*ln(S_resid)
      if (trackErr) e = fabsf(nv - po);
      pot[gi] = nv;
      cohStore(&biasOut[gi], 10.0f * INV_LN2 * (nv - nrm[gi]));
    }
    if (trackErr && tid < 64) {
      e = waveReduceSum(e);
      if (tid == 0) cohStore(&errpart[bid], e);
    }
  };

  int ep = 0;
  for (int it = 0; it < MAXIT; ++it) {
    stageBias(vb);                           // u-phase bias -> LDS
    if (it == 0) halfstep_online(xfr, ByP, x2, u, ub, true);
    else         halfstep_fast(xfr, ByP, x2, u, ub, true);
    gridBarrier(bar, ++ep);
    if (bid == 0 && tid < 64) {              // errpart complete after barrier
      float ts = cohLoad(&errpart[tid]) + cohLoad(&errpart[tid + 64]) +
                 cohLoad(&errpart[tid + 128]) + cohLoad(&errpart[tid + 192]);
      ts = waveReduceSum(ts);
      if (tid == 0) cohStoreI(&bar[288], (ts * 0.25f < 0.1f) ? 1 : 0);
    }
    stageBias(ub);                           // v-phase bias -> LDS
    if (it == 0) halfstep_online(yfr, BxP, y2, v, vb, false);
    else         halfstep_fast(yfr, BxP, y2, v, vb, false);
    gridBarrier(bar, ++ep);
    if (tid == 0) sdone = cohLoadI(&bar[288]);
    __syncthreads();
    if (sdone) break;                        // freeze u,v (matches reference)
  }
}

// Single fused epilogue: exact fp32 C, pi = exp((u+v-C)*10), cost partials.
__global__ __launch_bounds__(256) void final_kernel(const float* __restrict__ x,
                                                    const float* __restrict__ y,
                                                    const float* __restrict__ x2,
                                                    const float* __restrict__ y2,
                                                    const float* __restrict__ u,
                                                    const float* __restrict__ v,
                                                    float* __restrict__ C,
                                                    float* __restrict__ pi,
                                                    float* __restrict__ costpart) {
  __shared__ float xs[64][33];
  __shared__ float ys[64][33];
  int t = threadIdx.x;
  int b = blockIdx.z;
  int i0 = blockIdx.x * 64;
  int j0 = blockIdx.y * 64;
  const float4* xg = (const float4*)(x + ((size_t)b * P + i0) * 32);
  const float4* yg = (const float4*)(y + ((size_t)b * P + j0) * 32);
#pragma unroll
  for (int k = 0; k < 2; ++k) {
    int f4 = t + k * 256;
    int row = f4 >> 3;
    int col = (f4 & 7) << 2;
    float4 xv = xg[f4];
    xs[row][col] = xv.x; xs[row][col + 1] = xv.y; xs[row][col + 2] = xv.z; xs[row][col + 3] = xv.w;
    float4 yv = yg[f4];
    ys[row][col] = yv.x; ys[row][col + 1] = yv.y; ys[row][col + 2] = yv.z; ys[row][col + 3] = yv.w;
  }
  __syncthreads();
  int ti = t >> 4, tj = t & 15;
  int ib = ti * 4, jb = tj * 4;
  float acc[4][4];
#pragma unroll
  for (int a = 0; a < 4; ++a)
#pragma unroll
    for (int bb = 0; bb < 4; ++bb) acc[a][bb] = 0.f;
#pragma unroll 8
  for (int k = 0; k < 32; ++k) {
    float xa[4], yb[4];
#pragma unroll
    for (int a = 0; a < 4; ++a) xa[a] = xs[ib + a][k];
#pragma unroll
    for (int bb = 0; bb < 4; ++bb) yb[bb] = ys[jb + bb][k];
#pragma unroll
    for (int a = 0; a < 4; ++a)
#pragma unroll
      for (int bb = 0; bb < 4; ++bb) acc[a][bb] = fmaf(xa[a], yb[bb], acc[a][bb]);
  }
  float y2r[4], vr[4];
#pragma unroll
  for (int bb = 0; bb < 4; ++bb) {
    y2r[bb] = y2[b * P + j0 + jb + bb];
    vr[bb] = v[b * P + j0 + jb + bb];
  }
  float costacc = 0.f;
#pragma unroll
  for (int a = 0; a < 4; ++a) {
    int gi = b * P + i0 + ib + a;
    float x2r = x2[gi];
    float ur = u[gi];
    float4 co, po;
    co.x = x2r + y2r[0] - 2.f * acc[a][0];
    co.y = x2r + y2r[1] - 2.f * acc[a][1];
    co.z = x2r + y2r[2] - 2.f * acc[a][2];
    co.w = x2r + y2r[3] - 2.f * acc[a][3];
    po.x = __expf((ur + vr[0] - co.x) * 10.f);
    po.y = __expf((ur + vr[1] - co.y) * 10.f);
    po.z = __expf((ur + vr[2] - co.z) * 10.f);
    po.w = __expf((ur + vr[3] - co.w) * 10.f);
    costacc += po.x * co.x + po.y * co.y + po.z * co.z + po.w * co.w;
    float* crow = C + (size_t)gi * P + j0;
    ((float4*)crow)[tj] = co;
    float* prow = pi + (size_t)gi * P + j0;
    ((float4*)prow)[tj] = po;
  }
  costacc = waveReduceSum(costacc);
  __shared__ float red[4];
  if ((t & 63) == 0) red[t >> 6] = costacc;
  __syncthreads();
  if (t == 0)
    costpart[((size_t)b * 48 + blockIdx.y) * 48 + blockIdx.x] =
        red[0] + red[1] + red[2] + red[3];
}

__global__ __launch_bounds__(256) void cost_kernel(const float* __restrict__ costpart,
                                                   float* __restrict__ cost) {
  __shared__ float red[4];
  int t = threadIdx.x;
  for (int b = 0; b < BATCH; ++b) {
    float loc = 0.f;
    for (int idx = t; idx < 2304; idx += 256) loc += costpart[b * 2304 + idx];
    loc = waveReduceSum(loc);
    if ((t & 63) == 0) red[t >> 6] = loc;
    __syncthreads();
    if (t == 0) cost[b] = red[0] + red[1] + red[2] + red[3];
    __syncthreads();
  }
}

extern "C" void kernel_launch(void* const* d_in, const int* in_sizes, int n_in,
                              void* d_out, int out_size, void* d_ws, size_t ws_size,
                              hipStream_t stream) {
  (void)in_sizes; (void)n_in; (void)out_size; (void)ws_size;
  const float* x = (const float*)d_in[0];
  const float* y = (const float*)d_in[1];
  float* out = (float*)d_out;
  float* cost = out;                          // [4]
  float* pi = out + 4;                        // [4*3072*3072]
  float* C = pi + (size_t)BATCH * P * P;      // [4*3072*3072]

  float* u = (float*)d_ws;                    // 12288
  int* bar = (int*)(u + NROW);                // 512 ints: tree counters/gen/done
  float* v = (float*)(bar + 512);             // 12288
  float* ub = v + NROW;                       // 12288  (10/ln2*(u - x2))
  float* vb = ub + NROW;                      // 12288  (10/ln2*(v - y2))
  float* x2 = vb + NROW;                      // 12288
  float* y2 = x2 + NROW;                      // 12288
  float* errpart = y2 + NROW;                 // 256
  float* costpart = errpart + NBLK;           // 9216

  // fp16 fragment-packed scratch lives in the C output region (written last)
  _Float16* xh = (_Float16*)C;                // [768 tiles][1 KB] = 20/ln2 * x
  _Float16* yh = xh + (size_t)NROW * 32;      // [768 tiles][1 KB] = y

  // zero u + barrier state (harness poisons ws each call)
  hipMemsetAsync(d_ws, 0, (size_t)NROW * sizeof(float) + 512 * sizeof(int), stream);

  float lmn = logf(1.0f / 3072.0f + 1e-8f);   // log_mu == log_nu

  prep_kernel<<<384, 256, 0, stream>>>(x, y, xh, yh, x2, y2, vb);
  sinkhorn_kernel<<<NBLK, 512, 0, stream>>>(xh, yh, u, v, ub, vb, x2, y2,
                                            errpart, bar, lmn);
  final_kernel<<<dim3(48, 48, 4), 256, 0, stream>>>(x, y, x2, y2, u, v, C, pi, costpart);
  cost_kernel<<<1, 256, 0, stream>>>(costpart, cost);
}

// Round 9
// 1428.592 us; speedup vs baseline: 2.5835x; 1.0988x over previous
//
#include <hip/hip_runtime.h>
#include <math.h>

#define BATCH 4
#define P 3072
#define NROW (BATCH * P)        // 12288
#define NTILE (NROW / 16)       // 768 row-tiles of 16 rows
#define TPB (P / 16)            // 192 tiles per batch
#define MAXIT 50
#define NBLK 256                // persistent blocks, 1 per CU (proven resident)
#define RPB 48                  // rows per block (3 row-tiles)
#define WAVES 8                 // 512 threads (proven shape)
#define CTW 24                  // col-tiles per wave (8 waves x 24 x 16 = 3072 cols)

#define LN2 0.69314718055994531f
#define INV_LN2 1.44269504088896341f

typedef _Float16 f16x8 __attribute__((ext_vector_type(8)));
typedef float f32x4 __attribute__((ext_vector_type(4)));

__device__ inline float waveReduceSum(float v) {
#pragma unroll
  for (int off = 32; off > 0; off >>= 1) v += __shfl_xor(v, off, 64);
  return v;
}
__device__ inline float fexp2(float x) { return __builtin_amdgcn_exp2f(x); }
__device__ inline float flog2(float x) { return __builtin_amdgcn_logf(x); }  // v_log_f32 = log2

// Agent-coherent (sc1) accessors: read/write at the L3 coherence point.
// Only cross-block data (bias, errpart, done machinery) pays this cost.
__device__ inline float cohLoad(const float* p) {
  return __hip_atomic_load(p, __ATOMIC_RELAXED, __HIP_MEMORY_SCOPE_AGENT);
}
__device__ inline void cohStore(float* p, float val) {
  __hip_atomic_store(p, val, __ATOMIC_RELAXED, __HIP_MEMORY_SCOPE_AGENT);
}
__device__ inline int cohLoadI(const int* p) {
  return __hip_atomic_load(p, __ATOMIC_RELAXED, __HIP_MEMORY_SCOPE_AGENT);
}
__device__ inline void cohStoreI(int* p, int val) {
  __hip_atomic_store(p, val, __ATOMIC_RELAXED, __HIP_MEMORY_SCOPE_AGENT);
}

// Fence-free PER-BATCH barrier (64 blocks): 8 groups x 8, monotonic counters.
// __syncthreads() drains vmcnt before arrival, so this block's sc1 stores are
// at the coherence point before the generation flip. No L2 invalidation ever.
// bb ints (per-batch 256-int region): [g*16] 8 group counters (64 B apart),
// [128] root, [144] gen.
__device__ inline void batchBarrier(int* bb, int target, int local) {
  __syncthreads();                         // drains vmcnt: sc1 stores visible
  if (threadIdx.x == 0) {
    __builtin_amdgcn_sched_barrier(0);
    int g = local >> 3;                    // 8 groups of 8 blocks
    int old = __hip_atomic_fetch_add(&bb[g * 16], 1, __ATOMIC_RELAXED,
                                     __HIP_MEMORY_SCOPE_AGENT);
    if ((old & 7) == 7) {                  // last of this 8-group, this round
      int r = __hip_atomic_fetch_add(&bb[128], 1, __ATOMIC_RELAXED,
                                     __HIP_MEMORY_SCOPE_AGENT);
      if ((r & 7) == 7)                    // last group of this batch
        cohStoreI(&bb[144], target);
    }
    while (cohLoadI(&bb[144]) < target) __builtin_amdgcn_s_sleep(1);
    __builtin_amdgcn_sched_barrier(0);
  }
  __syncthreads();
}

// Pack x/y into MFMA-fragment-major fp16 tiles: frag[tile][g][r][8] (1 KB/tile);
// lane l loads its fragment for tile T at byte T*1024 + l*16 (coalesced 1 KB).
// x pre-scaled by 20/ln2 -> MFMA yields the base-2 LSE cross term directly.
__global__ __launch_bounds__(256) void prep_kernel(const float* __restrict__ x,
                                                   const float* __restrict__ y,
                                                   _Float16* __restrict__ xh,
                                                   _Float16* __restrict__ yh,
                                                   float* __restrict__ x2,
                                                   float* __restrict__ y2,
                                                   float* __restrict__ vb) {
  int t = threadIdx.x;
  int lane = t & 63;
  int g = lane >> 4, r = lane & 15;
  int tileG = blockIdx.x * 4 + (t >> 6);     // 0..1535 (x tiles then y tiles)
  int isY = tileG >= NTILE;
  int tile = isY ? (tileG - NTILE) : tileG;
  const float* src = isY ? y : x;
  int row = tile * 16 + r;
  const float* p = src + (size_t)row * 32 + g * 8;
  float4 v0 = *(const float4*)p;
  float4 v1 = *(const float4*)(p + 4);
  float sq = v0.x * v0.x + v0.y * v0.y + v0.z * v0.z + v0.w * v0.w +
             v1.x * v1.x + v1.y * v1.y + v1.z * v1.z + v1.w * v1.w;
  sq += __shfl_xor(sq, 16, 64);
  sq += __shfl_xor(sq, 32, 64);              // lanes with same r hold the row sum
  float scale = isY ? 1.0f : 20.0f * INV_LN2;
  f16x8 h;
  h[0] = (_Float16)(scale * v0.x); h[1] = (_Float16)(scale * v0.y);
  h[2] = (_Float16)(scale * v0.z); h[3] = (_Float16)(scale * v0.w);
  h[4] = (_Float16)(scale * v1.x); h[5] = (_Float16)(scale * v1.y);
  h[6] = (_Float16)(scale * v1.z); h[7] = (_Float16)(scale * v1.w);
  _Float16* dst = (isY ? yh : xh) + (size_t)tile * 512 + lane * 8;
  *(f16x8*)dst = h;
  if (lane < 16) {
    if (isY) { y2[row] = sq; vb[row] = -10.0f * INV_LN2 * sq; }  // v=0 bias
    else     { x2[row] = sq; }
  }
}

// Persistent Sinkhorn loop. 256 blocks x 512 threads (proven resident config);
// block owns 48 rows of x AND of y; 8 waves partition the 3072 cols (24
// col-tiles each). Data barriers are PER-BATCH (64 blocks): u-phase of batch b
// only needs batch b's vb. Global done uses iteration-tagged slots: each batch
// leader posts err[it]; the 4th poster computes gdone[it]; blocks poll
// gdone[it] at iteration end (normally already set -> one sc1 load).
// it=0: online-max path. it>=1: fixed-offset path (offset = prev row LSE from
// the previous potential, folded into the MFMA C operand; 1 exp2 + 1 add per
// element, branch-free). acc consumed per row-tile (VGPR ~84, no spill).
__global__ __launch_bounds__(512, 2) void sinkhorn_kernel(
    const _Float16* __restrict__ xh, const _Float16* __restrict__ yh,
    float* __restrict__ u, float* __restrict__ v,
    float* __restrict__ ub, float* __restrict__ vb,
    const float* __restrict__ x2, const float* __restrict__ y2,
    float* __restrict__ errpart, int* __restrict__ bar,
    int* __restrict__ gcount, int* __restrict__ gdone,
    float* __restrict__ berr, float lmn) {
  int tid = threadIdx.x;
  int lane = tid & 63;
  int w = tid >> 6;                          // 0..7
  int rsel = lane & 15;
  int g = lane >> 4;
  int bid = blockIdx.x;
  int b = bid >> 6;                          // 64 blocks per batch
  int local = bid & 63;
  int* bbar = bar + b * 256;                 // this batch's barrier region
  int tile0 = bid * 3;
  int gr0 = bid * RPB;
  // A-fragments for both phases: loaded ONCE, live in registers for 50 iters.
  f16x8 xfr[3], yfr[3];
#pragma unroll
  for (int rt = 0; rt < 3; ++rt) {
    xfr[rt] = *(const f16x8*)(xh + (size_t)(tile0 + rt) * 512 + lane * 8);
    yfr[rt] = *(const f16x8*)(yh + (size_t)(tile0 + rt) * 512 + lane * 8);
  }
  size_t jbase = ((size_t)(b * TPB + w * CTW)) * 512 + lane * 8;
  const _Float16* BxP = xh + jbase;
  const _Float16* ByP = yh + jbase;
  int sboff = w * (CTW * 16) + rsel;         // this wave's bias base in LDS

  __shared__ float sb[P];                    // 12 KB staged bias (this batch)
  __shared__ float lm[WAVES][RPB], ls[WAVES][RPB];
  __shared__ int sdone;

  // stage biasIn[b*P .. +3071] -> sb via 6 coalesced sc1 loads per thread
  auto stageBias = [&](const float* biasIn) {
    const float* bp = biasIn + b * P;
#pragma unroll
    for (int k = 0; k < 6; ++k) sb[tid + k * 512] = cohLoad(&bp[tid + k * 512]);
    __syncthreads();
  };

  // ---- iteration-0 halfstep: online max (proven path) ----
  auto halfstep_online = [&](const f16x8* afr, const _Float16* Bp,
                             const float* nrm, float* pot, float* biasOut, bool trackErr) {
    float m[3][4], s[3][4];
#pragma unroll
    for (int rt = 0; rt < 3; ++rt)
#pragma unroll
      for (int r = 0; r < 4; ++r) { m[rt][r] = -1e30f; s[rt][r] = 0.f; }
#pragma unroll 2
    for (int c = 0; c < 6; ++c) {
      f16x8 bfr[4];
      float bb[4];
#pragma unroll
      for (int t4 = 0; t4 < 4; ++t4) {
        bfr[t4] = *(const f16x8*)(Bp + ((size_t)(c * 4 + t4) << 9));
        bb[t4] = sb[sboff + (c * 4 + t4) * 16];
      }
#pragma unroll
      for (int rt = 0; rt < 3; ++rt) {
        f32x4 acc[4];
#pragma unroll
        for (int t4 = 0; t4 < 4; ++t4) {
          f32x4 ci = {bb[t4], bb[t4], bb[t4], bb[t4]};
          acc[t4] = __builtin_amdgcn_mfma_f32_16x16x32_f16(afr[rt], bfr[t4], ci, 0, 0, 0);
        }
#pragma unroll
        for (int r = 0; r < 4; ++r) {
          float a0 = acc[0][r], a1 = acc[1][r], a2 = acc[2][r], a3 = acc[3][r];
          float cm = fmaxf(fmaxf(a0, a1), fmaxf(a2, a3));
          float nm = fmaxf(m[rt][r], cm);
          s[rt][r] = s[rt][r] * fexp2(m[rt][r] - nm) +
                     fexp2(a0 - nm) + fexp2(a1 - nm) + fexp2(a2 - nm) + fexp2(a3 - nm);
          m[rt][r] = nm;
        }
      }
    }
#pragma unroll
    for (int rt = 0; rt < 3; ++rt)
#pragma unroll
      for (int r = 0; r < 4; ++r) {
#pragma unroll
        for (int o = 1; o < 16; o <<= 1) {
          float om = __shfl_xor(m[rt][r], o, 64);
          float os = __shfl_xor(s[rt][r], o, 64);
          float nm = fmaxf(m[rt][r], om);
          s[rt][r] = s[rt][r] * fexp2(m[rt][r] - nm) + os * fexp2(om - nm);
          m[rt][r] = nm;
        }
      }
    __syncthreads();
    if (rsel == 0) {
#pragma unroll
      for (int rt = 0; rt < 3; ++rt)
#pragma unroll
        for (int r = 0; r < 4; ++r) {
          lm[w][rt * 16 + g * 4 + r] = m[rt][r];
          ls[w][rt * 16 + g * 4 + r] = s[rt][r];
        }
    }
    __syncthreads();
    float e = 0.f;
    if (tid < RPB) {
      float M = lm[0][tid], S = ls[0][tid];
#pragma unroll
      for (int w2 = 1; w2 < WAVES; ++w2) {
        float om = lm[w2][tid], os = ls[w2][tid];
        float nm = fmaxf(M, om);
        S = S * fexp2(M - nm) + os * fexp2(om - nm);
        M = nm;
      }
      float L2v = M + flog2(S);
      int gi = gr0 + tid;
      float nv = 0.1f * lmn + nrm[gi] - 0.1f * LN2 * L2v;
      if (trackErr) e = fabsf(nv - pot[gi]);
      pot[gi] = nv;
      cohStore(&biasOut[gi], 10.0f * INV_LN2 * (nv - nrm[gi]));
    }
    if (trackErr && tid < 64) {
      e = waveReduceSum(e);
      if (tid == 0) cohStore(&errpart[bid], e);
    }
  };

  // ---- it>=1 halfstep: fixed-offset LSE, branch-free, 1 exp2/element ----
  auto halfstep_fast = [&](const f16x8* afr, const _Float16* Bp,
                           const float* nrm, float* pot, float* biasOut, bool trackErr) {
    float off[3][4];                         // prev row LSE (base 2), from prev potential
#pragma unroll
    for (int rt = 0; rt < 3; ++rt)
#pragma unroll
      for (int r = 0; r < 4; ++r) {
        int row = gr0 + rt * 16 + g * 4 + r;
        off[rt][r] = 10.0f * INV_LN2 * (0.1f * lmn + nrm[row] - pot[row]);
      }
    float s[3][4];
#pragma unroll
    for (int rt = 0; rt < 3; ++rt)
#pragma unroll
      for (int r = 0; r < 4; ++r) s[rt][r] = 0.f;
#pragma unroll 2
    for (int c = 0; c < 6; ++c) {
      f16x8 bfr[4];
      float bb[4];
#pragma unroll
      for (int t4 = 0; t4 < 4; ++t4) {
        bfr[t4] = *(const f16x8*)(Bp + ((size_t)(c * 4 + t4) << 9));
        bb[t4] = sb[sboff + (c * 4 + t4) * 16];
      }
#pragma unroll
      for (int rt = 0; rt < 3; ++rt) {       // consume acc per row-tile: low pressure
        f32x4 acc[4];
#pragma unroll
        for (int t4 = 0; t4 < 4; ++t4) {
          f32x4 ci = {bb[t4] - off[rt][0], bb[t4] - off[rt][1],
                      bb[t4] - off[rt][2], bb[t4] - off[rt][3]};
          acc[t4] = __builtin_amdgcn_mfma_f32_16x16x32_f16(afr[rt], bfr[t4], ci, 0, 0, 0);
        }
#pragma unroll
        for (int r = 0; r < 4; ++r)
          s[rt][r] += (fexp2(acc[0][r]) + fexp2(acc[1][r])) +
                      (fexp2(acc[2][r]) + fexp2(acc[3][r]));
      }
    }
    // pure-sum butterfly over the 16-lane col groups
#pragma unroll
    for (int rt = 0; rt < 3; ++rt)
#pragma unroll
      for (int r = 0; r < 4; ++r) {
#pragma unroll
        for (int o = 1; o < 16; o <<= 1)
          s[rt][r] += __shfl_xor(s[rt][r], o, 64);
      }
    __syncthreads();
    if (rsel == 0) {
#pragma unroll
      for (int rt = 0; rt < 3; ++rt)
#pragma unroll
        for (int r = 0; r < 4; ++r) ls[w][rt * 16 + g * 4 + r] = s[rt][r];
    }
    __syncthreads();
    float e = 0.f;
    if (tid < RPB) {
      float S = ls[0][tid];
#pragma unroll
      for (int w2 = 1; w2 < WAVES; ++w2) S += ls[w2][tid];
      int gi = gr0 + tid;
      float po = pot[gi];
      float nv = po - 0.1f * LN2 * flog2(S);   // pot_new = pot_prev - eps*ln(S_resid)
      if (trackErr) e = fabsf(nv - po);
      pot[gi] = nv;
      cohStore(&biasOut[gi], 10.0f * INV_LN2 * (nv - nrm[gi]));
    }
    if (trackErr && tid < 64) {
      e = waveReduceSum(e);
      if (tid == 0) cohStore(&errpart[bid], e);
    }
  };

  int ep = 0;
  for (int it = 0; it < MAXIT; ++it) {
    stageBias(vb);                           // u-phase bias -> LDS
    if (it == 0) halfstep_online(xfr, ByP, x2, u, ub, true);
    else         halfstep_fast(xfr, ByP, x2, u, ub, true);
    batchBarrier(bbar, ++ep, local);
    if (local == 0 && tid < 64) {            // batch leader: post err for iter it
      float e = cohLoad(&errpart[b * 64 + tid]);
      e = waveReduceSum(e);
      if (tid == 0) {
        cohStore(&berr[b], e);
        asm volatile("s_waitcnt vmcnt(0)");  // berr visible before the count bump
        int r = __hip_atomic_fetch_add(&gcount[it], 1, __ATOMIC_RELAXED,
                                       __HIP_MEMORY_SCOPE_AGENT);
        if (r == 3) {                        // 4th batch: decide
          float ts = cohLoad(&berr[0]) + cohLoad(&berr[1]) +
                     cohLoad(&berr[2]) + cohLoad(&berr[3]);
          cohStoreI(&gdone[it], (ts * 0.25f < 0.1f) ? 2 : 1);
        }
      }
    }
    stageBias(ub);                           // v-phase bias -> LDS
    if (it == 0) halfstep_online(yfr, BxP, y2, v, vb, false);
    else         halfstep_fast(yfr, BxP, y2, v, vb, false);
    batchBarrier(bbar, ++ep, local);
    if (tid == 0) {                          // global done for iter it (normally set)
      int gd;
      while ((gd = cohLoadI(&gdone[it])) == 0) __builtin_amdgcn_s_sleep(1);
      sdone = (gd == 2);
    }
    __syncthreads();
    if (sdone) break;                        // freeze u,v (matches reference)
  }
}

// Single fused epilogue: exact fp32 C, pi = exp((u+v-C)*10), cost partials.
__global__ __launch_bounds__(256) void final_kernel(const float* __restrict__ x,
                                                    const float* __restrict__ y,
                                                    const float* __restrict__ x2,
                                                    const float* __restrict__ y2,
                                                    const float* __restrict__ u,
                                                    const float* __restrict__ v,
                                                    float* __restrict__ C,
                                                    float* __restrict__ pi,
                                                    float* __restrict__ costpart) {
  __shared__ float xs[64][33];
  __shared__ float ys[64][33];
  int t = threadIdx.x;
  int b = blockIdx.z;
  int i0 = blockIdx.x * 64;
  int j0 = blockIdx.y * 64;
  const float4* xg = (const float4*)(x + ((size_t)b * P + i0) * 32);
  const float4* yg = (const float4*)(y + ((size_t)b * P + j0) * 32);
#pragma unroll
  for (int k = 0; k < 2; ++k) {
    int f4 = t + k * 256;
    int row = f4 >> 3;
    int col = (f4 & 7) << 2;
    float4 xv = xg[f4];
    xs[row][col] = xv.x; xs[row][col + 1] = xv.y; xs[row][col + 2] = xv.z; xs[row][col + 3] = xv.w;
    float4 yv = yg[f4];
    ys[row][col] = yv.x; ys[row][col + 1] = yv.y; ys[row][col + 2] = yv.z; ys[row][col + 3] = yv.w;
  }
  __syncthreads();
  int ti = t >> 4, tj = t & 15;
  int ib = ti * 4, jb = tj * 4;
  float acc[4][4];
#pragma unroll
  for (int a = 0; a < 4; ++a)
#pragma unroll
    for (int bb = 0; bb < 4; ++bb) acc[a][bb] = 0.f;
#pragma unroll 8
  for (int k = 0; k < 32; ++k) {
    float xa[4], yb[4];
#pragma unroll
    for (int a = 0; a < 4; ++a) xa[a] = xs[ib + a][k];
#pragma unroll
    for (int bb = 0; bb < 4; ++bb) yb[bb] = ys[jb + bb][k];
#pragma unroll
    for (int a = 0; a < 4; ++a)
#pragma unroll
      for (int bb = 0; bb < 4; ++bb) acc[a][bb] = fmaf(xa[a], yb[bb], acc[a][bb]);
  }
  float y2r[4], vr[4];
#pragma unroll
  for (int bb = 0; bb < 4; ++bb) {
    y2r[bb] = y2[b * P + j0 + jb + bb];
    vr[bb] = v[b * P + j0 + jb + bb];
  }
  float costacc = 0.f;
#pragma unroll
  for (int a = 0; a < 4; ++a) {
    int gi = b * P + i0 + ib + a;
    float x2r = x2[gi];
    float ur = u[gi];
    float4 co, po;
    co.x = x2r + y2r[0] - 2.f * acc[a][0];
    co.y = x2r + y2r[1] - 2.f * acc[a][1];
    co.z = x2r + y2r[2] - 2.f * acc[a][2];
    co.w = x2r + y2r[3] - 2.f * acc[a][3];
    po.x = __expf((ur + vr[0] - co.x) * 10.f);
    po.y = __expf((ur + vr[1] - co.y) * 10.f);
    po.z = __expf((ur + vr[2] - co.z) * 10.f);
    po.w = __expf((ur + vr[3] - co.w) * 10.f);
    costacc += po.x * co.x + po.y * co.y + po.z * co.z + po.w * co.w;
    float* crow = C + (size_t)gi * P + j0;
    ((float4*)crow)[tj] = co;
    float* prow = pi + (size_t)gi * P + j0;
    ((float4*)prow)[tj] = po;
  }
  costacc = waveReduceSum(costacc);
  __shared__ float red[4];
  if ((t & 63) == 0) red[t >> 6] = costacc;
  __syncthreads();
  if (t == 0)
    costpart[((size_t)b * 48 + blockIdx.y) * 48 + blockIdx.x] =
        red[0] + red[1] + red[2] + red[3];
}

__global__ __launch_bounds__(256) void cost_kernel(const float* __restrict__ costpart,
                                                   float* __restrict__ cost) {
  __shared__ float red[4];
  int t = threadIdx.x;
  for (int b = 0; b < BATCH; ++b) {
    float loc = 0.f;
    for (int idx = t; idx < 2304; idx += 256) loc += costpart[b * 2304 + idx];
    loc = waveReduceSum(loc);
    if ((t & 63) == 0) red[t >> 6] = loc;
    __syncthreads();
    if (t == 0) cost[b] = red[0] + red[1] + red[2] + red[3];
    __syncthreads();
  }
}

extern "C" void kernel_launch(void* const* d_in, const int* in_sizes, int n_in,
                              void* d_out, int out_size, void* d_ws, size_t ws_size,
                              hipStream_t stream) {
  (void)in_sizes; (void)n_in; (void)out_size; (void)ws_size;
  const float* x = (const float*)d_in[0];
  const float* y = (const float*)d_in[1];
  float* out = (float*)d_out;
  float* cost = out;                          // [4]
  float* pi = out + 4;                        // [4*3072*3072]
  float* C = pi + (size_t)BATCH * P * P;      // [4*3072*3072]

  float* u = (float*)d_ws;                    // 12288
  int* bar = (int*)(u + NROW);                // 4 batches x 256 ints
  int* gcount = bar + 1024;                   // 64 ints (per-iteration counters)
  int* gdone = gcount + 64;                   // 64 ints (0=unset,1=go,2=stop)
  float* berr = (float*)(gdone + 64);         // 4 floats
  float* v = berr + 4;                        // 12288
  float* ub = v + NROW;                       // 12288  (10/ln2*(u - x2))
  float* vb = ub + NROW;                      // 12288  (10/ln2*(v - y2))
  float* x2 = vb + NROW;                      // 12288
  float* y2 = x2 + NROW;                      // 12288
  float* errpart = y2 + NROW;                 // 256
  float* costpart = errpart + NBLK;           // 9216

  // fp16 fragment-packed scratch lives in the C output region (written last)
  _Float16* xh = (_Float16*)C;                // [768 tiles][1 KB] = 20/ln2 * x
  _Float16* yh = xh + (size_t)NROW * 32;      // [768 tiles][1 KB] = y

  // zero u + barrier/done state (harness poisons ws each call):
  // u (NROW*4 B) + bar (4096 B) + gcount (256 B) + gdone (256 B) + berr (16 B)
  hipMemsetAsync(d_ws, 0, (size_t)NROW * sizeof(float) + 4624, stream);

  float lmn = logf(1.0f / 3072.0f + 1e-8f);   // log_mu == log_nu

  prep_kernel<<<384, 256, 0, stream>>>(x, y, xh, yh, x2, y2, vb);
  sinkhorn_kernel<<<NBLK, 512, 0, stream>>>(xh, yh, u, v, ub, vb, x2, y2,
                                            errpart, bar, gcount, gdone, berr, lmn);
  final_kernel<<<dim3(48, 48, 4), 256, 0, stream>>>(x, y, x2, y2, u, v, C, pi, costpart);
  cost_kernel<<<1, 256, 0, stream>>>(costpart, cost);
}